// Round 3
// baseline (1193.036 us; speedup 1.0000x reference)
//
#include <hip/hip_runtime.h>
#include <hip/hip_bf16.h>

typedef unsigned short u16;
typedef unsigned int u32;
typedef __attribute__((ext_vector_type(8))) short s16x8;
typedef __attribute__((ext_vector_type(4))) float f32x4;
typedef __attribute__((ext_vector_type(2))) float f32x2;
typedef __attribute__((ext_vector_type(4))) unsigned short u16x4;

#define DEV static __device__ __forceinline__

// ---------- helpers ----------
DEV u16 bf16_rne(float f) {
  u32 u = __float_as_uint(f);
  u32 r = 0x7FFFu + ((u >> 16) & 1u);
  return (u16)((u + r) >> 16);
}
DEV float bf16_to_f32(u16 h) { return __uint_as_float(((u32)h) << 16); }

typedef const __attribute__((address_space(1))) u32* gptr_t;
typedef __attribute__((address_space(3))) u32* lptr_t;
DEV void gload_lds16(const void* g, void* l) {
  __builtin_amdgcn_global_load_lds((gptr_t)g, (lptr_t)l, 16, 0, 0);
}

// ---------- workspace layout (bytes) ----------
#define OFF_XSPLIT  0ull
#define OFF_WSPLIT  33554432ull
#define OFF_QKF     83886080ull
#define OFF_VB      150994944ull
#define OFF_QB      167772160ull
#define OFF_KB      184549376ull
#define OFF_VT      201326592ull
#define OFF_COS     218103808ull
#define OFF_SIN     219152384ull

// ---------- split fp32 -> bf16 hi + bf16 lo ----------
__global__ __launch_bounds__(256) void k_split(const float* __restrict__ in,
                                               u16* __restrict__ hi, u16* __restrict__ lo, int n) {
  int i = blockIdx.x * 256 + threadIdx.x;
  int stride = gridDim.x * 256;
  for (; i < n; i += stride) {
    float x = in[i];
    u16 h = bf16_rne(x);
    float xh = bf16_to_f32(h);
    hi[i] = h;
    lo[i] = bf16_rne(x - xh);
  }
}

// ---------- RoPE cos/sin table: (n, 64) ----------
__global__ __launch_bounds__(256) void k_rope_table(float* __restrict__ cosT, float* __restrict__ sinT) {
  int tid = blockIdx.x * 256 + threadIdx.x;
  if (tid >= 4096 * 64) return;
  int n = tid >> 6, j = tid & 63;
  int t = n >> 9, hh = (n >> 5) & 15, ww = n & 31;
  float pos, e;
  if (j < 32)      { pos = (float)t;  e = (float)j * (1.0f / 32.0f); }
  else if (j < 48) { pos = (float)hh; e = (float)(j - 32) * (1.0f / 16.0f); }
  else             { pos = (float)ww; e = (float)(j - 48) * (1.0f / 16.0f); }
  float inv = (float)pow(10000.0, -(double)e);
  float f = pos * inv;
  cosT[tid] = cosf(f);
  sinT[tid] = sinf(f);
}

// ---------- 256x256 8-wave GEMM, 4-phase K-tiles, counted vmcnt, st_16x32 swizzle ----------
// C[M][NX*256] = sum_seg A_seg (row-major, K-stride 2048) . B_seg^T (row-major, K-stride 2048)
// NSEG segments of K=2048 each (NT = NSEG*32 K-tiles of BK=64).
// LDS tile layout: 16x32 bf16 subtiles (1024B), within-subtile byte ^= ((r&8)<<2).
template<int NSEG, int MODE, int NX>
__global__ __launch_bounds__(512, 2) void k_gemm8(
    const u16* __restrict__ A0, const u16* __restrict__ A1, const u16* __restrict__ A2,
    const u16* __restrict__ B0, const u16* __restrict__ B1, const u16* __restrict__ B2,
    const float* __restrict__ bias,
    float* __restrict__ outF, u16* __restrict__ outV)
{
  constexpr int NT = NSEG * 32;
  __shared__ u16 smem[2][2][16384];   // [buf][A=0/B=1][256x64 swizzled]

  const int tid = threadIdx.x;
  const int lane = tid & 63;
  const int lr = lane & 15, lg = lane >> 4;
  const int w = tid >> 6;
  const int wr = w >> 2;        // 0..1  (M wave)
  const int wc = w & 3;         // 0..3  (N wave)

  // XCD-bijective swizzle (gridDim.x % 8 == 0 for both launches)
  const int nwg = gridDim.x;
  const int qq = nwg >> 3;
  const int swz = (blockIdx.x & 7) * qq + (blockIdx.x >> 3);
  const int bx = swz % NX, by = swz / NX;
  const int row0 = by * 256, col0 = bx * 256;

  const size_t aoff0 = (size_t)row0 * 2048;
  const size_t boff0 = (size_t)col0 * 2048;

  // stage decode: linear 16B chunk -> (row,col) under swizzled-subtile layout
  u32 goff[4];
#pragma unroll
  for (int i = 0; i < 4; ++i) {
    int L = (i * 512 + tid) * 16;            // byte offset in 32KB tile
    int sub = L >> 10;
    int r = (L >> 6) & 15;
    int cb = (L & 63) ^ ((r & 8) << 2);      // inverse swizzle -> logical byte-in-row
    int row = (sub >> 1) * 16 + r;
    int col = (sub & 1) * 32 + (cb >> 1);
    goff[i] = (u32)row * 2048u + (u32)col;
  }

  // fragment read offset (u16 units within one 32KB tile)
  const int swi = ((lr * 64 + lg * 16) ^ ((lr & 8) << 2)) >> 1;

  f32x4 acc[8][4];
#pragma unroll
  for (int m = 0; m < 8; m++)
#pragma unroll
    for (int n = 0; n < 4; n++) acc[m][n] = f32x4{0.f, 0.f, 0.f, 0.f};

  auto stage = [&](int nt, int nb) __attribute__((always_inline)) {
    int s = nt >> 5;
    u32 kk = (u32)(nt & 31) << 6;
    const u16* As_ = A0; const u16* Bs_ = B0;
    if (NSEG >= 2 && s == 1) { As_ = A1; Bs_ = B1; }
    if (NSEG >= 3 && s == 2) { As_ = A2; Bs_ = B2; }
#pragma unroll
    for (int i = 0; i < 4; ++i)
      gload_lds16(As_ + aoff0 + goff[i] + kk, &smem[nb][0][(i * 512 + tid) * 8]);
#pragma unroll
    for (int i = 0; i < 4; ++i)
      gload_lds16(Bs_ + boff0 + goff[i] + kk, &smem[nb][1][(i * 512 + tid) * 8]);
  };

  stage(0, 0);   // prologue

#define LDSA(BUF, SM, KS) (*(const s16x8*)&smem[BUF][0][(((SM) * 2 + (KS)) * 512) + swi])
#define LDSB(BUF, SN, KS) (*(const s16x8*)&smem[BUF][1][(((SN) * 2 + (KS)) * 512) + swi])

#pragma unroll 2
  for (int kt = 0; kt < NT; ++kt) {
    const int buf = kt & 1;
    if (kt + 1 < NT) {
      stage(kt + 1, buf ^ 1);
      asm volatile("s_waitcnt vmcnt(8)" ::: "memory");
    } else {
      asm volatile("s_waitcnt vmcnt(0)" ::: "memory");
    }
    __builtin_amdgcn_s_barrier();
    asm volatile("" ::: "memory");

    s16x8 aR[4][2], bR[4][2];
    // ---- P0: A band0 + B band0 -> quadrant (0,0)
#pragma unroll
    for (int fm = 0; fm < 4; ++fm)
#pragma unroll
      for (int ks = 0; ks < 2; ++ks) aR[fm][ks] = LDSA(buf, wr * 8 + fm, ks);
#pragma unroll
    for (int fn = 0; fn < 2; ++fn)
#pragma unroll
      for (int ks = 0; ks < 2; ++ks) bR[fn][ks] = LDSB(buf, wc * 4 + fn, ks);
    __builtin_amdgcn_s_setprio(1);
#pragma unroll
    for (int fm = 0; fm < 4; ++fm)
#pragma unroll
      for (int fn = 0; fn < 2; ++fn)
#pragma unroll
        for (int ks = 0; ks < 2; ++ks)
          acc[fm][fn] = __builtin_amdgcn_mfma_f32_16x16x32_bf16(aR[fm][ks], bR[fn][ks], acc[fm][fn], 0, 0, 0);
    __builtin_amdgcn_s_setprio(0);
    // ---- P1: B band1 -> quadrant (0,1)
#pragma unroll
    for (int fn = 2; fn < 4; ++fn)
#pragma unroll
      for (int ks = 0; ks < 2; ++ks) bR[fn][ks] = LDSB(buf, wc * 4 + fn, ks);
    __builtin_amdgcn_s_setprio(1);
#pragma unroll
    for (int fm = 0; fm < 4; ++fm)
#pragma unroll
      for (int fn = 2; fn < 4; ++fn)
#pragma unroll
        for (int ks = 0; ks < 2; ++ks)
          acc[fm][fn] = __builtin_amdgcn_mfma_f32_16x16x32_bf16(aR[fm][ks], bR[fn][ks], acc[fm][fn], 0, 0, 0);
    __builtin_amdgcn_s_setprio(0);
    // ---- P2: A band1 -> quadrant (1,1)
#pragma unroll
    for (int fm = 0; fm < 4; ++fm)
#pragma unroll
      for (int ks = 0; ks < 2; ++ks) aR[fm][ks] = LDSA(buf, wr * 8 + 4 + fm, ks);
    __builtin_amdgcn_s_setprio(1);
#pragma unroll
    for (int fm = 0; fm < 4; ++fm)
#pragma unroll
      for (int fn = 2; fn < 4; ++fn)
#pragma unroll
        for (int ks = 0; ks < 2; ++ks)
          acc[4 + fm][fn] = __builtin_amdgcn_mfma_f32_16x16x32_bf16(aR[fm][ks], bR[fn][ks], acc[4 + fm][fn], 0, 0, 0);
    __builtin_amdgcn_s_setprio(0);
    // ---- P3: quadrant (1,0)
    __builtin_amdgcn_s_setprio(1);
#pragma unroll
    for (int fm = 0; fm < 4; ++fm)
#pragma unroll
      for (int fn = 0; fn < 2; ++fn)
#pragma unroll
        for (int ks = 0; ks < 2; ++ks)
          acc[4 + fm][fn] = __builtin_amdgcn_mfma_f32_16x16x32_bf16(aR[fm][ks], bR[fn][ks], acc[4 + fm][fn], 0, 0, 0);
    __builtin_amdgcn_s_setprio(0);

    asm volatile("" ::: "memory");
    __builtin_amdgcn_s_barrier();   // all reads of buf done -> next tile may stage into it
  }
#undef LDSA
#undef LDSB

  // epilogue
#pragma unroll
  for (int fm = 0; fm < 8; ++fm) {
#pragma unroll
    for (int fn = 0; fn < 4; ++fn) {
      int col = col0 + wc * 64 + fn * 16 + lr;
      float b = bias[col];
      int rowb = row0 + wr * 128 + fm * 16 + lg * 4;
#pragma unroll
      for (int r = 0; r < 4; ++r) {
        float v = acc[fm][fn][r] + b;
        int row = rowb + r;
        if constexpr (MODE == 0) {
          if (col0 < 4096) outF[(size_t)row * 4096 + col] = v;
          else             outV[(size_t)row * 2048 + (col - 4096)] = bf16_rne(v);
        } else {
          outF[(size_t)row * 2048 + col] = v;
        }
      }
    }
  }
}

// ---------- RMSNorm (fp32) + RoPE + bf16 cast for q,k. One wave per (n,h). ----------
__global__ __launch_bounds__(256) void k_norm_rope(
    const float* __restrict__ qkf, const float* __restrict__ qw, const float* __restrict__ kw,
    const float* __restrict__ cosT, const float* __restrict__ sinT,
    u16* __restrict__ qb, u16* __restrict__ kb)
{
  int gw = (blockIdx.x * 256 + threadIdx.x) >> 6;
  int lane = threadIdx.x & 63;
  int n = gw >> 4;
  int h = gw & 15;
  float c = cosT[n * 64 + lane];
  float s = sinT[n * 64 + lane];
#pragma unroll
  for (int p = 0; p < 2; ++p) {
    const float* src = qkf + (size_t)n * 4096 + p * 2048 + h * 128;
    f32x2 xv = *(const f32x2*)(src + lane * 2);
    float xr = xv[0], xi = xv[1];
    float ss = xr * xr + xi * xi;
#pragma unroll
    for (int m = 1; m < 64; m <<= 1) ss += __shfl_xor(ss, m, 64);
    float r = 1.0f / sqrtf(ss * (1.0f / 128.0f) + 1e-6f);
    const float* wgt = p ? kw : qw;
    float yr = xr * r * wgt[lane * 2];
    float yi = xi * r * wgt[lane * 2 + 1];
    float o0 = yr * c - yi * s;
    float o1 = yr * s + yi * c;
    u16* dst = (p ? kb : qb) + (size_t)h * 4096 * 128 + (size_t)n * 128 + lane * 2;
    *(u32*)dst = ((u32)bf16_rne(o1) << 16) | bf16_rne(o0);
  }
}

// ---------- V transpose: (n, h*128+d) -> (h, d, n) ----------
__global__ __launch_bounds__(256) void k_transpose_v(const u16* __restrict__ vb, u16* __restrict__ vt) {
  __shared__ u16 Vs[64][136];
  int h = blockIdx.y;
  int n0 = blockIdx.x * 64;
  int t = threadIdx.x;
  int nl = t >> 2, d0 = (t & 3) * 32;
  const u16* src = vb + (size_t)(n0 + nl) * 2048 + h * 128 + d0;
#pragma unroll
  for (int i = 0; i < 8; ++i)
    *(u16x4*)&Vs[nl][d0 + i * 4] = *(const u16x4*)(src + i * 4);
  __syncthreads();
  int d = t >> 1, nc = (t & 1) * 32;
  u16* dst = vt + (size_t)h * 128 * 4096 + (size_t)d * 4096 + n0 + nc;
#pragma unroll
  for (int j4 = 0; j4 < 8; ++j4) {
    u16x4 o;
    o.x = Vs[nc + j4 * 4 + 0][d];
    o.y = Vs[nc + j4 * 4 + 1][d];
    o.z = Vs[nc + j4 * 4 + 2][d];
    o.w = Vs[nc + j4 * 4 + 3][d];
    *(u16x4*)(dst + j4 * 4) = o;
  }
}

// ---------- flash attention: blocks (32 q-tiles, 16 heads), 4 waves x 32 q-rows ----------
__global__ __launch_bounds__(256, 2) void k_attn(
    const u16* __restrict__ qb, const u16* __restrict__ kb, const u16* __restrict__ vt,
    u16* __restrict__ obf)
{
  __shared__ u16 Ks[64 * 128];
  __shared__ u16 Vs[128 * 64];
  __shared__ u16 Ps[4][32 * 72];
  const int t = threadIdx.x;
  const int lane = t & 63;
  const int lr = lane & 15, lg = lane >> 4;
  const int w = t >> 6;
  const int h = blockIdx.y;
  const int qw0 = blockIdx.x * 128 + w * 32;

  const u16* qh = qb + (size_t)h * 4096 * 128;
  const u16* kh = kb + (size_t)h * 4096 * 128;
  const u16* vh = vt + (size_t)h * 128 * 4096;

  s16x8 qf[2][4];
#pragma unroll
  for (int qi = 0; qi < 2; ++qi)
#pragma unroll
    for (int ks = 0; ks < 4; ++ks)
      qf[qi][ks] = *(const s16x8*)(qh + (size_t)(qw0 + qi * 16 + lr) * 128 + ks * 32 + lg * 8);

  f32x4 oacc[2][8];
#pragma unroll
  for (int i = 0; i < 2; i++)
#pragma unroll
    for (int j = 0; j < 8; j++) oacc[i][j] = f32x4{0.f, 0.f, 0.f, 0.f};
  float M[2][4], L[2][4];
#pragma unroll
  for (int i = 0; i < 2; i++)
#pragma unroll
    for (int r = 0; r < 4; r++) { M[i][r] = -__builtin_inff(); L[i][r] = 0.f; }

  const float scale_bf = bf16_to_f32(bf16_rne(0.08838834764831845f));

  for (int kt = 0; kt < 64; ++kt) {
#pragma unroll
    for (int i = 0; i < 4; ++i) {
      int c = t + i * 256;
      int row = c >> 4;
      int cc = (c & 15) ^ (row & 7);
      gload_lds16(kh + (size_t)(kt * 64 + row) * 128 + cc * 8, &Ks[c * 8]);
    }
#pragma unroll
    for (int i = 0; i < 4; ++i) {
      int c = t + i * 256;
      int d = c >> 3;
      int cc = (c & 7) ^ (d & 7);
      gload_lds16(vh + (size_t)d * 4096 + kt * 64 + cc * 8, &Vs[c * 8]);
    }
    __syncthreads();

    f32x4 sfr[2][4];
    __builtin_amdgcn_s_setprio(1);
#pragma unroll
    for (int qi = 0; qi < 2; ++qi)
#pragma unroll
      for (int kbl = 0; kbl < 4; ++kbl) {
        f32x4 a = f32x4{0.f, 0.f, 0.f, 0.f};
#pragma unroll
        for (int ks = 0; ks < 4; ++ks) {
          int key = kbl * 16 + lr;
          int byteoff = (key * 256 + (ks * 32 + lg * 8) * 2) ^ ((key & 7) << 4);
          s16x8 bfr = *(const s16x8*)((const char*)Ks + byteoff);
          a = __builtin_amdgcn_mfma_f32_16x16x32_bf16(qf[qi][ks], bfr, a, 0, 0, 0);
        }
        sfr[qi][kbl] = a;
      }
    __builtin_amdgcn_s_setprio(0);

#pragma unroll
    for (int qi = 0; qi < 2; ++qi) {
      float mx[4];
#pragma unroll
      for (int r = 0; r < 4; ++r) {
#pragma unroll
        for (int kbl = 0; kbl < 4; ++kbl) {
          float sv = bf16_to_f32(bf16_rne(sfr[qi][kbl][r])) * scale_bf;
          sfr[qi][kbl][r] = bf16_to_f32(bf16_rne(sv));
        }
        float m0 = fmaxf(fmaxf(sfr[qi][0][r], sfr[qi][1][r]), fmaxf(sfr[qi][2][r], sfr[qi][3][r]));
#pragma unroll
        for (int m = 1; m < 16; m <<= 1) m0 = fmaxf(m0, __shfl_xor(m0, m, 64));
        mx[r] = m0;
      }
      bool ok = (mx[0] - M[qi][0] <= 8.f) && (mx[1] - M[qi][1] <= 8.f) &&
                (mx[2] - M[qi][2] <= 8.f) && (mx[3] - M[qi][3] <= 8.f);
      if (!__all(ok)) {
#pragma unroll
        for (int r = 0; r < 4; ++r) {
          float nm = fmaxf(M[qi][r], mx[r]);
          float fac = __expf(M[qi][r] - nm);
          M[qi][r] = nm;
          L[qi][r] *= fac;
#pragma unroll
          for (int db = 0; db < 8; ++db) oacc[qi][db][r] *= fac;
        }
      }
      float sum[4] = {0.f, 0.f, 0.f, 0.f};
#pragma unroll
      for (int kbl = 0; kbl < 4; ++kbl)
#pragma unroll
        for (int r = 0; r < 4; ++r) {
          float p = __expf(sfr[qi][kbl][r] - M[qi][r]);
          sum[r] += p;
          Ps[w][(qi * 16 + lg * 4 + r) * 72 + kbl * 16 + lr] = bf16_rne(p);
        }
#pragma unroll
      for (int r = 0; r < 4; ++r) {
        float s4 = sum[r];
#pragma unroll
        for (int m = 1; m < 16; m <<= 1) s4 += __shfl_xor(s4, m, 64);
        L[qi][r] += s4;
      }
    }

    asm volatile("s_waitcnt lgkmcnt(0)" ::: "memory");

    s16x8 pa[2][2];
#pragma unroll
    for (int qi = 0; qi < 2; ++qi)
#pragma unroll
      for (int ks = 0; ks < 2; ++ks)
        pa[qi][ks] = *(const s16x8*)&Ps[w][(qi * 16 + lr) * 72 + ks * 32 + lg * 8];
    __builtin_amdgcn_s_setprio(1);
#pragma unroll
    for (int db = 0; db < 8; ++db)
#pragma unroll
      for (int ks = 0; ks < 2; ++ks) {
        int d = db * 16 + lr;
        int byteoff = (d * 128 + (ks * 32 + lg * 8) * 2) ^ ((d & 7) << 4);
        s16x8 vb8 = *(const s16x8*)((const char*)Vs + byteoff);
        oacc[0][db] = __builtin_amdgcn_mfma_f32_16x16x32_bf16(pa[0][ks], vb8, oacc[0][db], 0, 0, 0);
        oacc[1][db] = __builtin_amdgcn_mfma_f32_16x16x32_bf16(pa[1][ks], vb8, oacc[1][db], 0, 0, 0);
      }
    __builtin_amdgcn_s_setprio(0);
    __syncthreads();
  }

#pragma unroll
  for (int qi = 0; qi < 2; ++qi) {
    float rl[4];
#pragma unroll
    for (int r = 0; r < 4; ++r) rl[r] = 1.0f / L[qi][r];
#pragma unroll
    for (int db = 0; db < 8; ++db) {
      int d = db * 16 + lr;
#pragma unroll
      for (int r = 0; r < 4; ++r) {
        int q = qw0 + qi * 16 + lg * 4 + r;
        obf[(size_t)q * 2048 + h * 128 + d] = bf16_rne(oacc[qi][db][r] * rl[r]);
      }
    }
  }
}

// ---------- launch ----------
extern "C" void kernel_launch(void* const* d_in, const int* in_sizes, int n_in,
                              void* d_out, int out_size, void* d_ws, size_t ws_size,
                              hipStream_t stream) {
  const float* x      = (const float*)d_in[0];
  const float* qkv_w  = (const float*)d_in[1];
  const float* qkv_b  = (const float*)d_in[2];
  const float* qnw    = (const float*)d_in[3];
  const float* knw    = (const float*)d_in[4];
  const float* proj_w = (const float*)d_in[5];
  const float* proj_b = (const float*)d_in[6];
  float* out = (float*)d_out;
  char* ws = (char*)d_ws;

  u16* xs    = (u16*)(ws + OFF_XSPLIT);
  u16* wsp   = (u16*)(ws + OFF_WSPLIT);
  u16* pws   = (u16*)(ws + OFF_WSPLIT);
  float* qkf = (float*)(ws + OFF_QKF);
  u16* vb16  = (u16*)(ws + OFF_VB);
  u16* qb16  = (u16*)(ws + OFF_QB);
  u16* kb16  = (u16*)(ws + OFF_KB);
  u16* vt16  = (u16*)(ws + OFF_VT);
  u16* obf   = (u16*)(ws + OFF_XSPLIT);
  float* cosT = (float*)(ws + OFF_COS);
  float* sinT = (float*)(ws + OFF_SIN);

  u16* xsl = xs + (size_t)4096 * 2048;
  u16* wl  = wsp + (size_t)6144 * 2048;
  u16* pl  = pws + (size_t)2048 * 2048;

  k_split<<<2048, 256, 0, stream>>>(x, xs, xsl, 4096 * 2048);
  k_split<<<2048, 256, 0, stream>>>(qkv_w, wsp, wl, 6144 * 2048);
  k_rope_table<<<1024, 256, 0, stream>>>(cosT, sinT);

  // QKV: Xh.Wh + Xh.Wl + Xl.Wh   (grid 16x24 = 384 blocks)
  k_gemm8<3, 0, 24><<<384, 512, 0, stream>>>(xs, xs, xsl, wsp, wl, wsp,
                                             qkv_b, qkf, vb16);

  k_split<<<2048, 256, 0, stream>>>(proj_w, pws, pl, 2048 * 2048);
  k_norm_rope<<<16384, 256, 0, stream>>>(qkf, qnw, knw, cosT, sinT, qb16, kb16);
  k_transpose_v<<<dim3(64, 16), 256, 0, stream>>>(vb16, vt16);
  k_attn<<<dim3(32, 16), 256, 0, stream>>>(qb16, kb16, vt16, obf);

  // proj: O.Ph + O.Pl   (grid 16x8 = 128 blocks)
  k_gemm8<2, 1, 8><<<128, 512, 0, stream>>>(obf, obf, obf, pws, pl, pws,
                                            proj_b, out, nullptr);
}

// Round 4
// 1125.643 us; speedup vs baseline: 1.0599x; 1.0599x over previous
//
#include <hip/hip_runtime.h>
#include <hip/hip_bf16.h>

typedef unsigned short u16;
typedef unsigned int u32;
typedef __attribute__((ext_vector_type(8))) short s16x8;
typedef __attribute__((ext_vector_type(4))) float f32x4;
typedef __attribute__((ext_vector_type(2))) float f32x2;
typedef __attribute__((ext_vector_type(4))) unsigned short u16x4;

#define DEV static __device__ __forceinline__

// ---------- helpers ----------
DEV u16 bf16_rne(float f) {
  u32 u = __float_as_uint(f);
  u32 r = 0x7FFFu + ((u >> 16) & 1u);
  return (u16)((u + r) >> 16);
}
DEV float bf16_to_f32(u16 h) { return __uint_as_float(((u32)h) << 16); }

typedef const __attribute__((address_space(1))) u32* gptr_t;
typedef __attribute__((address_space(3))) u32* lptr_t;
DEV void gload_lds16(const void* g, void* l) {
  __builtin_amdgcn_global_load_lds((gptr_t)g, (lptr_t)l, 16, 0, 0);
}

// ---------- workspace layout (bytes) ----------
#define OFF_XSPLIT  0ull
#define OFF_WSPLIT  33554432ull
#define OFF_QKF     83886080ull
#define OFF_VB      150994944ull
#define OFF_QB      167772160ull
#define OFF_KB      184549376ull
#define OFF_VT      201326592ull
#define OFF_COS     218103808ull
#define OFF_SIN     219152384ull

// ---------- split fp32 -> bf16 hi + bf16 lo ----------
__global__ __launch_bounds__(256) void k_split(const float* __restrict__ in,
                                               u16* __restrict__ hi, u16* __restrict__ lo, int n) {
  int i = blockIdx.x * 256 + threadIdx.x;
  int stride = gridDim.x * 256;
  for (; i < n; i += stride) {
    float x = in[i];
    u16 h = bf16_rne(x);
    float xh = bf16_to_f32(h);
    hi[i] = h;
    lo[i] = bf16_rne(x - xh);
  }
}

// ---------- RoPE cos/sin table: (n, 64) ----------
__global__ __launch_bounds__(256) void k_rope_table(float* __restrict__ cosT, float* __restrict__ sinT) {
  int tid = blockIdx.x * 256 + threadIdx.x;
  if (tid >= 4096 * 64) return;
  int n = tid >> 6, j = tid & 63;
  int t = n >> 9, hh = (n >> 5) & 15, ww = n & 31;
  float pos, e;
  if (j < 32)      { pos = (float)t;  e = (float)j * (1.0f / 32.0f); }
  else if (j < 48) { pos = (float)hh; e = (float)(j - 32) * (1.0f / 16.0f); }
  else             { pos = (float)ww; e = (float)(j - 48) * (1.0f / 16.0f); }
  float inv = (float)pow(10000.0, -(double)e);
  float f = pos * inv;
  cosT[tid] = cosf(f);
  sinT[tid] = sinf(f);
}

// ---------- 256x256 8-wave GEMM, fine 4-phase schedule, counted vmcnt ----------
// C = sum_seg A_seg (row-major, K-stride 2048) . B_seg^T (row-major, K-stride 2048)
// LDS: [buf2][A/B][half2][128x64 bf16, 16x32 subtiles, byte ^= ((r&8)<<2)]
// Per K-tile (BK=64): 4 phases; phase = {reads; barrier; stage 1 half-tile; 16 MFMA}.
// Stage schedule: group t -> p0:A0(t+1) p1:A1(t+1) p2:B0(t+2) p3:B1(t+2).
// vmcnt(2) once per K-tile (before p3 barrier) keeps 3 half-tiles in flight.
template<int NSEG, int MODE, int NX>
__global__ __launch_bounds__(512, 2) void k_gemm8(
    const u16* __restrict__ A0, const u16* __restrict__ A1, const u16* __restrict__ A2,
    const u16* __restrict__ B0p, const u16* __restrict__ B1p, const u16* __restrict__ B2p,
    const float* __restrict__ bias,
    float* __restrict__ outF, u16* __restrict__ outV)
{
  constexpr int NT = NSEG * 32;
  __shared__ u16 smem[65536];   // 128 KiB

  const int tid = threadIdx.x;
  const int lane = tid & 63;
  const int lr = lane & 15, lg = lane >> 4;
  const int w = tid >> 6;
  const int wr = w >> 2;        // 0..1  (M wave)
  const int wc = w & 3;         // 0..3  (N wave)
  const int hb = wc >> 1;       // B half
  const int cb4 = (wc & 1) * 4; // B subtile row-block base within half

  // XCD-bijective swizzle (gridDim.x % 8 == 0 for both launches)
  const int nwg = gridDim.x;
  const int qq = nwg >> 3;
  const int swz = (blockIdx.x & 7) * qq + (blockIdx.x >> 3);
  const int bx = swz % NX, by = swz / NX;
  const int row0 = by * 256, col0 = bx * 256;

  const size_t aoff0 = (size_t)row0 * 2048;
  const size_t boff0 = (size_t)col0 * 2048;

  // stage decode: 2 chunks/thread per 16KiB half-tile, inverse-swizzled source
  u32 goff[2];
#pragma unroll
  for (int i = 0; i < 2; ++i) {
    int L = (i * 512 + tid) * 16;            // byte offset in half-tile
    int sub = L >> 10;
    int r = (L >> 6) & 15;
    int cb = (L & 63) ^ ((r & 8) << 2);
    int row = (sub >> 1) * 16 + r;           // 0..127 within half
    int col = (sub & 1) * 32 + (cb >> 1);
    goff[i] = (u32)row * 2048u + (u32)col;
  }

  const int swi = lr * 32 + ((lg * 8) ^ ((lr & 8) << 1));   // u16 offset in subtile

  f32x4 acc[8][4];
#pragma unroll
  for (int m = 0; m < 8; m++)
#pragma unroll
    for (int n = 0; n < 4; n++) acc[m][n] = f32x4{0.f, 0.f, 0.f, 0.f};

  auto stage = [&](int u, int ab, int h) __attribute__((always_inline)) {
    int s = u >> 5;
    const u16* base;
    if (ab == 0) {
      base = A0;
      if (NSEG >= 2 && s == 1) base = A1;
      if (NSEG >= 3 && s == 2) base = A2;
      base += aoff0;
    } else {
      base = B0p;
      if (NSEG >= 2 && s == 1) base = B1p;
      if (NSEG >= 3 && s == 2) base = B2p;
      base += boff0;
    }
    base += (size_t)h * (128 * 2048) + (u32)(u & 31) * 64;
    u32 ldst = (u32)(u & 1) * 32768u + (u32)ab * 16384u + (u32)h * 8192u + (u32)tid * 8u;
    gload_lds16(base + goff[0], &smem[ldst]);
    gload_lds16(base + goff[1], &smem[ldst + 4096]);
  };

  // prologue: A(0), B(0), B(1) = 12 loads; allow B(1) in flight
  stage(0, 0, 0); stage(0, 0, 1);
  stage(0, 1, 0); stage(0, 1, 1);
  stage(1, 1, 0); stage(1, 1, 1);
  asm volatile("s_waitcnt vmcnt(4)" ::: "memory");
  __builtin_amdgcn_s_barrier();
  asm volatile("" ::: "memory");

  for (int t = 0; t < NT; ++t) {
    const u32 bufo = (u32)(t & 1) * 32768u;
    const u16* sA = &smem[bufo + (u32)wr * 8192u];
    const u16* sB = &smem[bufo + 16384u + (u32)hb * 8192u];
    s16x8 aR[4][2], bRa[2][2], bRb[2][2];

    // ---- p0: reads aR(mq=0) + bR(nq=0); MFMA quadrant (0,0)
#pragma unroll
    for (int fm = 0; fm < 4; ++fm)
#pragma unroll
      for (int ks = 0; ks < 2; ++ks) aR[fm][ks] = *(const s16x8*)&sA[(fm * 2 + ks) * 512 + swi];
#pragma unroll
    for (int fn = 0; fn < 2; ++fn)
#pragma unroll
      for (int ks = 0; ks < 2; ++ks) bRa[fn][ks] = *(const s16x8*)&sB[((cb4 + fn) * 2 + ks) * 512 + swi];
    __builtin_amdgcn_s_barrier();
    asm volatile("" ::: "memory");
    if (t + 1 < NT) stage(t + 1, 0, 0);
    __builtin_amdgcn_s_setprio(1);
#pragma unroll
    for (int fm = 0; fm < 4; ++fm)
#pragma unroll
      for (int fn = 0; fn < 2; ++fn)
#pragma unroll
        for (int ks = 0; ks < 2; ++ks)
          acc[fm][fn] = __builtin_amdgcn_mfma_f32_16x16x32_bf16(aR[fm][ks], bRa[fn][ks], acc[fm][fn], 0, 0, 0);
    __builtin_amdgcn_s_setprio(0);

    // ---- p1: reads bR(nq=1); MFMA quadrant (0,1)
#pragma unroll
    for (int fn = 0; fn < 2; ++fn)
#pragma unroll
      for (int ks = 0; ks < 2; ++ks) bRb[fn][ks] = *(const s16x8*)&sB[((cb4 + 2 + fn) * 2 + ks) * 512 + swi];
    __builtin_amdgcn_s_barrier();
    asm volatile("" ::: "memory");
    if (t + 1 < NT) stage(t + 1, 0, 1);
    __builtin_amdgcn_s_setprio(1);
#pragma unroll
    for (int fm = 0; fm < 4; ++fm)
#pragma unroll
      for (int fn = 0; fn < 2; ++fn)
#pragma unroll
        for (int ks = 0; ks < 2; ++ks)
          acc[fm][2 + fn] = __builtin_amdgcn_mfma_f32_16x16x32_bf16(aR[fm][ks], bRb[fn][ks], acc[fm][2 + fn], 0, 0, 0);
    __builtin_amdgcn_s_setprio(0);

    // ---- p2: reads aR(mq=1); MFMA quadrant (1,1)
#pragma unroll
    for (int fm = 0; fm < 4; ++fm)
#pragma unroll
      for (int ks = 0; ks < 2; ++ks) aR[fm][ks] = *(const s16x8*)&sA[((4 + fm) * 2 + ks) * 512 + swi];
    __builtin_amdgcn_s_barrier();
    asm volatile("" ::: "memory");
    if (t + 2 < NT) stage(t + 2, 1, 0);
    __builtin_amdgcn_s_setprio(1);
#pragma unroll
    for (int fm = 0; fm < 4; ++fm)
#pragma unroll
      for (int fn = 0; fn < 2; ++fn)
#pragma unroll
        for (int ks = 0; ks < 2; ++ks)
          acc[4 + fm][2 + fn] = __builtin_amdgcn_mfma_f32_16x16x32_bf16(aR[fm][ks], bRb[fn][ks], acc[4 + fm][2 + fn], 0, 0, 0);
    __builtin_amdgcn_s_setprio(0);

    // ---- p3: MFMA quadrant (1,0); counted vmcnt before barrier
    if (t + 2 < NT) asm volatile("s_waitcnt vmcnt(2)" ::: "memory");
    else            asm volatile("s_waitcnt vmcnt(0)" ::: "memory");
    __builtin_amdgcn_s_barrier();
    asm volatile("" ::: "memory");
    if (t + 2 < NT) stage(t + 2, 1, 1);
    __builtin_amdgcn_s_setprio(1);
#pragma unroll
    for (int fm = 0; fm < 4; ++fm)
#pragma unroll
      for (int fn = 0; fn < 2; ++fn)
#pragma unroll
        for (int ks = 0; ks < 2; ++ks)
          acc[4 + fm][fn] = __builtin_amdgcn_mfma_f32_16x16x32_bf16(aR[fm][ks], bRa[fn][ks], acc[4 + fm][fn], 0, 0, 0);
    __builtin_amdgcn_s_setprio(0);
  }

  // epilogue
#pragma unroll
  for (int fm = 0; fm < 8; ++fm) {
#pragma unroll
    for (int fn = 0; fn < 4; ++fn) {
      int col = col0 + wc * 64 + fn * 16 + lr;
      float b = bias[col];
      int rowb = row0 + wr * 128 + fm * 16 + lg * 4;
#pragma unroll
      for (int r = 0; r < 4; ++r) {
        float v = acc[fm][fn][r] + b;
        int row = rowb + r;
        if constexpr (MODE == 0) {
          if (col0 < 4096) outF[(size_t)row * 4096 + col] = v;
          else             outV[(size_t)row * 2048 + (col - 4096)] = bf16_rne(v);
        } else {
          outF[(size_t)row * 2048 + col] = v;
        }
      }
    }
  }
}

// ---------- RMSNorm (fp32) + RoPE + bf16 cast for q,k. One wave per (n,h). ----------
__global__ __launch_bounds__(256) void k_norm_rope(
    const float* __restrict__ qkf, const float* __restrict__ qw, const float* __restrict__ kw,
    const float* __restrict__ cosT, const float* __restrict__ sinT,
    u16* __restrict__ qb, u16* __restrict__ kb)
{
  int gw = (blockIdx.x * 256 + threadIdx.x) >> 6;
  int lane = threadIdx.x & 63;
  int n = gw >> 4;
  int h = gw & 15;
  float c = cosT[n * 64 + lane];
  float s = sinT[n * 64 + lane];
#pragma unroll
  for (int p = 0; p < 2; ++p) {
    const float* src = qkf + (size_t)n * 4096 + p * 2048 + h * 128;
    f32x2 xv = *(const f32x2*)(src + lane * 2);
    float xr = xv[0], xi = xv[1];
    float ss = xr * xr + xi * xi;
#pragma unroll
    for (int m = 1; m < 64; m <<= 1) ss += __shfl_xor(ss, m, 64);
    float r = 1.0f / sqrtf(ss * (1.0f / 128.0f) + 1e-6f);
    const float* wgt = p ? kw : qw;
    float yr = xr * r * wgt[lane * 2];
    float yi = xi * r * wgt[lane * 2 + 1];
    float o0 = yr * c - yi * s;
    float o1 = yr * s + yi * c;
    u16* dst = (p ? kb : qb) + (size_t)h * 4096 * 128 + (size_t)n * 128 + lane * 2;
    *(u32*)dst = ((u32)bf16_rne(o1) << 16) | bf16_rne(o0);
  }
}

// ---------- V transpose: (n, h*128+d) -> (h, d, n) ----------
__global__ __launch_bounds__(256) void k_transpose_v(const u16* __restrict__ vb, u16* __restrict__ vt) {
  __shared__ u16 Vs[64][136];
  int h = blockIdx.y;
  int n0 = blockIdx.x * 64;
  int t = threadIdx.x;
  int nl = t >> 2, d0 = (t & 3) * 32;
  const u16* src = vb + (size_t)(n0 + nl) * 2048 + h * 128 + d0;
#pragma unroll
  for (int i = 0; i < 8; ++i)
    *(u16x4*)&Vs[nl][d0 + i * 4] = *(const u16x4*)(src + i * 4);
  __syncthreads();
  int d = t >> 1, nc = (t & 1) * 32;
  u16* dst = vt + (size_t)h * 128 * 4096 + (size_t)d * 4096 + n0 + nc;
#pragma unroll
  for (int j4 = 0; j4 < 8; ++j4) {
    u16x4 o;
    o.x = Vs[nc + j4 * 4 + 0][d];
    o.y = Vs[nc + j4 * 4 + 1][d];
    o.z = Vs[nc + j4 * 4 + 2][d];
    o.w = Vs[nc + j4 * 4 + 3][d];
    *(u16x4*)(dst + j4 * 4) = o;
  }
}

// ---------- flash attention: blocks (32 q-tiles, 16 heads), 4 waves x 32 q-rows ----------
__global__ __launch_bounds__(256, 2) void k_attn(
    const u16* __restrict__ qb, const u16* __restrict__ kb, const u16* __restrict__ vt,
    u16* __restrict__ obf)
{
  __shared__ u16 Ks[64 * 128];
  __shared__ u16 Vs[128 * 64];
  __shared__ u16 Ps[4][32 * 72];
  const int t = threadIdx.x;
  const int lane = t & 63;
  const int lr = lane & 15, lg = lane >> 4;
  const int w = t >> 6;
  const int h = blockIdx.y;
  const int qw0 = blockIdx.x * 128 + w * 32;

  const u16* qh = qb + (size_t)h * 4096 * 128;
  const u16* kh = kb + (size_t)h * 4096 * 128;
  const u16* vh = vt + (size_t)h * 128 * 4096;

  s16x8 qf[2][4];
#pragma unroll
  for (int qi = 0; qi < 2; ++qi)
#pragma unroll
    for (int ks = 0; ks < 4; ++ks)
      qf[qi][ks] = *(const s16x8*)(qh + (size_t)(qw0 + qi * 16 + lr) * 128 + ks * 32 + lg * 8);

  f32x4 oacc[2][8];
#pragma unroll
  for (int i = 0; i < 2; i++)
#pragma unroll
    for (int j = 0; j < 8; j++) oacc[i][j] = f32x4{0.f, 0.f, 0.f, 0.f};
  float M[2][4], L[2][4];
#pragma unroll
  for (int i = 0; i < 2; i++)
#pragma unroll
    for (int r = 0; r < 4; r++) { M[i][r] = -__builtin_inff(); L[i][r] = 0.f; }

  const float scale_bf = bf16_to_f32(bf16_rne(0.08838834764831845f));

  for (int kt = 0; kt < 64; ++kt) {
#pragma unroll
    for (int i = 0; i < 4; ++i) {
      int c = t + i * 256;
      int row = c >> 4;
      int cc = (c & 15) ^ (row & 7);
      gload_lds16(kh + (size_t)(kt * 64 + row) * 128 + cc * 8, &Ks[c * 8]);
    }
#pragma unroll
    for (int i = 0; i < 4; ++i) {
      int c = t + i * 256;
      int d = c >> 3;
      int cc = (c & 7) ^ (d & 7);
      gload_lds16(vh + (size_t)d * 4096 + kt * 64 + cc * 8, &Vs[c * 8]);
    }
    __syncthreads();

    f32x4 sfr[2][4];
    __builtin_amdgcn_s_setprio(1);
#pragma unroll
    for (int qi = 0; qi < 2; ++qi)
#pragma unroll
      for (int kbl = 0; kbl < 4; ++kbl) {
        f32x4 a = f32x4{0.f, 0.f, 0.f, 0.f};
#pragma unroll
        for (int ks = 0; ks < 4; ++ks) {
          int key = kbl * 16 + lr;
          int byteoff = (key * 256 + (ks * 32 + lg * 8) * 2) ^ ((key & 7) << 4);
          s16x8 bfr = *(const s16x8*)((const char*)Ks + byteoff);
          a = __builtin_amdgcn_mfma_f32_16x16x32_bf16(qf[qi][ks], bfr, a, 0, 0, 0);
        }
        sfr[qi][kbl] = a;
      }
    __builtin_amdgcn_s_setprio(0);

#pragma unroll
    for (int qi = 0; qi < 2; ++qi) {
      float mx[4];
#pragma unroll
      for (int r = 0; r < 4; ++r) {
#pragma unroll
        for (int kbl = 0; kbl < 4; ++kbl) {
          float sv = bf16_to_f32(bf16_rne(sfr[qi][kbl][r])) * scale_bf;
          sfr[qi][kbl][r] = bf16_to_f32(bf16_rne(sv));
        }
        float m0 = fmaxf(fmaxf(sfr[qi][0][r], sfr[qi][1][r]), fmaxf(sfr[qi][2][r], sfr[qi][3][r]));
#pragma unroll
        for (int m = 1; m < 16; m <<= 1) m0 = fmaxf(m0, __shfl_xor(m0, m, 64));
        mx[r] = m0;
      }
      bool ok = (mx[0] - M[qi][0] <= 8.f) && (mx[1] - M[qi][1] <= 8.f) &&
                (mx[2] - M[qi][2] <= 8.f) && (mx[3] - M[qi][3] <= 8.f);
      if (!__all(ok)) {
#pragma unroll
        for (int r = 0; r < 4; ++r) {
          float nm = fmaxf(M[qi][r], mx[r]);
          float fac = __expf(M[qi][r] - nm);
          M[qi][r] = nm;
          L[qi][r] *= fac;
#pragma unroll
          for (int db = 0; db < 8; ++db) oacc[qi][db][r] *= fac;
        }
      }
      float sum[4] = {0.f, 0.f, 0.f, 0.f};
#pragma unroll
      for (int kbl = 0; kbl < 4; ++kbl)
#pragma unroll
        for (int r = 0; r < 4; ++r) {
          float p = __expf(sfr[qi][kbl][r] - M[qi][r]);
          sum[r] += p;
          Ps[w][(qi * 16 + lg * 4 + r) * 72 + kbl * 16 + lr] = bf16_rne(p);
        }
#pragma unroll
      for (int r = 0; r < 4; ++r) {
        float s4 = sum[r];
#pragma unroll
        for (int m = 1; m < 16; m <<= 1) s4 += __shfl_xor(s4, m, 64);
        L[qi][r] += s4;
      }
    }

    asm volatile("s_waitcnt lgkmcnt(0)" ::: "memory");

    s16x8 pa[2][2];
#pragma unroll
    for (int qi = 0; qi < 2; ++qi)
#pragma unroll
      for (int ks = 0; ks < 2; ++ks)
        pa[qi][ks] = *(const s16x8*)&Ps[w][(qi * 16 + lr) * 72 + ks * 32 + lg * 8];
    __builtin_amdgcn_s_setprio(1);
#pragma unroll
    for (int db = 0; db < 8; ++db)
#pragma unroll
      for (int ks = 0; ks < 2; ++ks) {
        int d = db * 16 + lr;
        int byteoff = (d * 128 + (ks * 32 + lg * 8) * 2) ^ ((d & 7) << 4);
        s16x8 vb8 = *(const s16x8*)((const char*)Vs + byteoff);
        oacc[0][db] = __builtin_amdgcn_mfma_f32_16x16x32_bf16(pa[0][ks], vb8, oacc[0][db], 0, 0, 0);
        oacc[1][db] = __builtin_amdgcn_mfma_f32_16x16x32_bf16(pa[1][ks], vb8, oacc[1][db], 0, 0, 0);
      }
    __builtin_amdgcn_s_setprio(0);
    __syncthreads();
  }

#pragma unroll
  for (int qi = 0; qi < 2; ++qi) {
    float rl[4];
#pragma unroll
    for (int r = 0; r < 4; ++r) rl[r] = 1.0f / L[qi][r];
#pragma unroll
    for (int db = 0; db < 8; ++db) {
      int d = db * 16 + lr;
#pragma unroll
      for (int r = 0; r < 4; ++r) {
        int q = qw0 + qi * 16 + lg * 4 + r;
        obf[(size_t)q * 2048 + h * 128 + d] = bf16_rne(oacc[qi][db][r] * rl[r]);
      }
    }
  }
}

// ---------- launch ----------
extern "C" void kernel_launch(void* const* d_in, const int* in_sizes, int n_in,
                              void* d_out, int out_size, void* d_ws, size_t ws_size,
                              hipStream_t stream) {
  const float* x      = (const float*)d_in[0];
  const float* qkv_w  = (const float*)d_in[1];
  const float* qkv_b  = (const float*)d_in[2];
  const float* qnw    = (const float*)d_in[3];
  const float* knw    = (const float*)d_in[4];
  const float* proj_w = (const float*)d_in[5];
  const float* proj_b = (const float*)d_in[6];
  float* out = (float*)d_out;
  char* ws = (char*)d_ws;

  u16* xs    = (u16*)(ws + OFF_XSPLIT);
  u16* wsp   = (u16*)(ws + OFF_WSPLIT);
  u16* pws   = (u16*)(ws + OFF_WSPLIT);
  float* qkf = (float*)(ws + OFF_QKF);
  u16* vb16  = (u16*)(ws + OFF_VB);
  u16* qb16  = (u16*)(ws + OFF_QB);
  u16* kb16  = (u16*)(ws + OFF_KB);
  u16* vt16  = (u16*)(ws + OFF_VT);
  u16* obf   = (u16*)(ws + OFF_XSPLIT);
  float* cosT = (float*)(ws + OFF_COS);
  float* sinT = (float*)(ws + OFF_SIN);

  u16* xsl = xs + (size_t)4096 * 2048;
  u16* wl  = wsp + (size_t)6144 * 2048;
  u16* pl  = pws + (size_t)2048 * 2048;

  k_split<<<2048, 256, 0, stream>>>(x, xs, xsl, 4096 * 2048);
  k_split<<<2048, 256, 0, stream>>>(qkv_w, wsp, wl, 6144 * 2048);
  k_rope_table<<<1024, 256, 0, stream>>>(cosT, sinT);

  // QKV: Xh.Wh + Xh.Wl + Xl.Wh   (grid 16x24 = 384 blocks)
  k_gemm8<3, 0, 24><<<384, 512, 0, stream>>>(xs, xs, xsl, wsp, wl, wsp,
                                             qkv_b, qkf, vb16);

  k_split<<<2048, 256, 0, stream>>>(proj_w, pws, pl, 2048 * 2048);
  k_norm_rope<<<16384, 256, 0, stream>>>(qkf, qnw, knw, cosT, sinT, qb16, kb16);
  k_transpose_v<<<dim3(64, 16), 256, 0, stream>>>(vb16, vt16);
  k_attn<<<dim3(32, 16), 256, 0, stream>>>(qb16, kb16, vt16, obf);

  // proj: O.Ph + O.Pl   (grid 16x8 = 128 blocks)
  k_gemm8<2, 1, 8><<<128, 512, 0, stream>>>(obf, obf, obf, pws, pl, pws,
                                            proj_b, out, nullptr);
}

// Round 5
// 839.244 us; speedup vs baseline: 1.4216x; 1.3413x over previous
//
#include <hip/hip_runtime.h>
#include <hip/hip_bf16.h>

typedef unsigned short u16;
typedef unsigned int u32;
typedef __attribute__((ext_vector_type(8))) short s16x8;
typedef __attribute__((ext_vector_type(4))) float f32x4;
typedef __attribute__((ext_vector_type(2))) float f32x2;
typedef __attribute__((ext_vector_type(4))) unsigned short u16x4;

#define DEV static __device__ __forceinline__

// ---------- helpers ----------
DEV u16 bf16_rne(float f) {
  u32 u = __float_as_uint(f);
  u32 r = 0x7FFFu + ((u >> 16) & 1u);
  return (u16)((u + r) >> 16);
}
DEV float bf16_to_f32(u16 h) { return __uint_as_float(((u32)h) << 16); }

typedef const __attribute__((address_space(1))) u32* gptr_t;
typedef __attribute__((address_space(3))) u32* lptr_t;
DEV void gload_lds16(const void* g, void* l) {
  __builtin_amdgcn_global_load_lds((gptr_t)g, (lptr_t)l, 16, 0, 0);
}

// ---------- workspace layout (bytes) ----------
#define OFF_XSPLIT  0ull
#define OFF_WSPLIT  33554432ull
#define OFF_QKF     83886080ull
#define OFF_VB      150994944ull
#define OFF_QB      167772160ull
#define OFF_KB      184549376ull
#define OFF_VT      201326592ull
#define OFF_COS     218103808ull
#define OFF_SIN     219152384ull

// ---------- split fp32 -> bf16 hi + bf16 lo ----------
__global__ __launch_bounds__(256) void k_split(const float* __restrict__ in,
                                               u16* __restrict__ hi, u16* __restrict__ lo, int n) {
  int i = blockIdx.x * 256 + threadIdx.x;
  int stride = gridDim.x * 256;
  for (; i < n; i += stride) {
    float x = in[i];
    u16 h = bf16_rne(x);
    float xh = bf16_to_f32(h);
    hi[i] = h;
    lo[i] = bf16_rne(x - xh);
  }
}

// ---------- RoPE cos/sin table: (n, 64) ----------
__global__ __launch_bounds__(256) void k_rope_table(float* __restrict__ cosT, float* __restrict__ sinT) {
  int tid = blockIdx.x * 256 + threadIdx.x;
  if (tid >= 4096 * 64) return;
  int n = tid >> 6, j = tid & 63;
  int t = n >> 9, hh = (n >> 5) & 15, ww = n & 31;
  float pos, e;
  if (j < 32)      { pos = (float)t;  e = (float)j * (1.0f / 32.0f); }
  else if (j < 48) { pos = (float)hh; e = (float)(j - 32) * (1.0f / 16.0f); }
  else             { pos = (float)ww; e = (float)(j - 48) * (1.0f / 16.0f); }
  float inv = (float)pow(10000.0, -(double)e);
  float f = pos * inv;
  cosT[tid] = cosf(f);
  sinT[tid] = sinf(f);
}

// ---------- bf16 GEMM, m97 structure: 128x128 tile, BK=32, 4 waves ----------
// 1-D grid (nwg % 8 == 0) with bijective XCD swizzle; NX = column tiles.
template<int MODE, int NX>
__global__ __launch_bounds__(256, 2) void k_gemm(
    const u16* __restrict__ A0, const u16* __restrict__ A1, const u16* __restrict__ A2,
    const u16* __restrict__ B0, const u16* __restrict__ B1, const u16* __restrict__ B2,
    int nseg, int K,
    const float* __restrict__ bias,
    float* __restrict__ outF, u16* __restrict__ outV)
{
  __shared__ u16 As[128 * 32];
  __shared__ u16 Bs[128 * 32];
  const int t = threadIdx.x;
  const int lane = t & 63;
  const int lr = lane & 15, lg = lane >> 4;
  const int w = t >> 6;
  const int wr = w >> 1, wc = w & 1;

  // T1: bijective XCD swizzle (consecutive swz per XCD share the A row-panel)
  const int nwg = gridDim.x;
  const int q8 = nwg >> 3;
  const int swz = (blockIdx.x & 7) * q8 + (blockIdx.x >> 3);
  const int bx = swz % NX, by = swz / NX;
  const int row0 = by * 128;
  const int col0 = bx * 128;

  f32x4 acc[4][4];
#pragma unroll
  for (int m = 0; m < 4; m++)
#pragma unroll
    for (int n = 0; n < 4; n++) acc[m][n] = f32x4{0.f, 0.f, 0.f, 0.f};

  const int c0 = t, c1 = t + 256;

  for (int s = 0; s < nseg; ++s) {
    const u16* Ab = (s == 0) ? A0 : (s == 1) ? A1 : A2;
    const u16* Bb = (s == 0) ? B0 : (s == 1) ? B1 : B2;
    const int nkb = K / 32;
    for (int kb = 0; kb < nkb; ++kb) {
      const int k0 = kb * 32;
      gload_lds16(Ab + (size_t)(row0 + (c0 >> 2)) * K + k0 + (c0 & 3) * 8, &As[c0 * 8]);
      gload_lds16(Ab + (size_t)(row0 + (c1 >> 2)) * K + k0 + (c1 & 3) * 8, &As[c1 * 8]);
      gload_lds16(Bb + (size_t)(col0 + (c0 >> 2)) * K + k0 + (c0 & 3) * 8, &Bs[c0 * 8]);
      gload_lds16(Bb + (size_t)(col0 + (c1 >> 2)) * K + k0 + (c1 & 3) * 8, &Bs[c1 * 8]);
      __syncthreads();
      s16x8 af[4], bf[4];
#pragma unroll
      for (int m = 0; m < 4; m++)
        af[m] = *(const s16x8*)&As[(wr * 64 + m * 16 + lr) * 32 + lg * 8];
#pragma unroll
      for (int n = 0; n < 4; n++)
        bf[n] = *(const s16x8*)&Bs[(wc * 64 + n * 16 + lr) * 32 + lg * 8];
      __builtin_amdgcn_s_setprio(1);
#pragma unroll
      for (int m = 0; m < 4; m++)
#pragma unroll
        for (int n = 0; n < 4; n++)
          acc[m][n] = __builtin_amdgcn_mfma_f32_16x16x32_bf16(af[m], bf[n], acc[m][n], 0, 0, 0);
      __builtin_amdgcn_s_setprio(0);
      __syncthreads();
    }
  }

#pragma unroll
  for (int m = 0; m < 4; m++) {
#pragma unroll
    for (int n = 0; n < 4; n++) {
      int col = col0 + wc * 64 + n * 16 + lr;
      float b = bias[col];
#pragma unroll
      for (int r = 0; r < 4; r++) {
        int row = row0 + wr * 64 + m * 16 + lg * 4 + r;
        float v = acc[m][n][r] + b;
        if constexpr (MODE == 0) {
          if (col < 4096) outF[(size_t)row * 4096 + col] = v;
          else            outV[(size_t)row * 2048 + (col - 4096)] = bf16_rne(v);
        } else {
          outF[(size_t)row * 2048 + col] = v;
        }
      }
    }
  }
}

// ---------- RMSNorm (fp32) + RoPE + bf16 cast for q,k. One wave per (n,h). ----------
__global__ __launch_bounds__(256) void k_norm_rope(
    const float* __restrict__ qkf, const float* __restrict__ qw, const float* __restrict__ kw,
    const float* __restrict__ cosT, const float* __restrict__ sinT,
    u16* __restrict__ qb, u16* __restrict__ kb)
{
  int gw = (blockIdx.x * 256 + threadIdx.x) >> 6;
  int lane = threadIdx.x & 63;
  int n = gw >> 4;
  int h = gw & 15;
  float c = cosT[n * 64 + lane];
  float s = sinT[n * 64 + lane];
#pragma unroll
  for (int p = 0; p < 2; ++p) {
    const float* src = qkf + (size_t)n * 4096 + p * 2048 + h * 128;
    f32x2 xv = *(const f32x2*)(src + lane * 2);
    float xr = xv[0], xi = xv[1];
    float ss = xr * xr + xi * xi;
#pragma unroll
    for (int m = 1; m < 64; m <<= 1) ss += __shfl_xor(ss, m, 64);
    float r = 1.0f / sqrtf(ss * (1.0f / 128.0f) + 1e-6f);
    const float* wgt = p ? kw : qw;
    float yr = xr * r * wgt[lane * 2];
    float yi = xi * r * wgt[lane * 2 + 1];
    float o0 = yr * c - yi * s;
    float o1 = yr * s + yi * c;
    u16* dst = (p ? kb : qb) + (size_t)h * 4096 * 128 + (size_t)n * 128 + lane * 2;
    *(u32*)dst = ((u32)bf16_rne(o1) << 16) | bf16_rne(o0);
  }
}

// ---------- V transpose: (n, h*128+d) -> (h, d, n) ----------
__global__ __launch_bounds__(256) void k_transpose_v(const u16* __restrict__ vb, u16* __restrict__ vt) {
  __shared__ u16 Vs[64][136];
  int h = blockIdx.y;
  int n0 = blockIdx.x * 64;
  int t = threadIdx.x;
  int nl = t >> 2, d0 = (t & 3) * 32;
  const u16* src = vb + (size_t)(n0 + nl) * 2048 + h * 128 + d0;
#pragma unroll
  for (int i = 0; i < 8; ++i)
    *(u16x4*)&Vs[nl][d0 + i * 4] = *(const u16x4*)(src + i * 4);
  __syncthreads();
  int d = t >> 1, nc = (t & 1) * 32;
  u16* dst = vt + (size_t)h * 128 * 4096 + (size_t)d * 4096 + n0 + nc;
#pragma unroll
  for (int j4 = 0; j4 < 8; ++j4) {
    u16x4 o;
    o.x = Vs[nc + j4 * 4 + 0][d];
    o.y = Vs[nc + j4 * 4 + 1][d];
    o.z = Vs[nc + j4 * 4 + 2][d];
    o.w = Vs[nc + j4 * 4 + 3][d];
    *(u16x4*)(dst + j4 * 4) = o;
  }
}

// ---------- flash attention: 512 blocks, head-local XCD mapping, 4 waves x 32 q-rows ----------
__global__ __launch_bounds__(256, 2) void k_attn(
    const u16* __restrict__ qb, const u16* __restrict__ kb, const u16* __restrict__ vt,
    u16* __restrict__ obf)
{
  __shared__ u16 Ks[64 * 128];
  __shared__ u16 Vs[128 * 64];
  __shared__ u16 Ps[4][32 * 72];
  const int t = threadIdx.x;
  const int lane = t & 63;
  const int lr = lane & 15, lg = lane >> 4;
  const int w = t >> 6;

  // head-local XCD mapping: all 32 q-tiles of a head land on one XCD
  const int bid = blockIdx.y * 32 + blockIdx.x;     // 0..511
  const int h = (bid & 7) + 8 * ((bid >> 3) >> 5);  // 0..15
  const int qt = (bid >> 3) & 31;                   // 0..31
  const int qw0 = qt * 128 + w * 32;

  const u16* qh = qb + (size_t)h * 4096 * 128;
  const u16* kh = kb + (size_t)h * 4096 * 128;
  const u16* vh = vt + (size_t)h * 128 * 4096;

  s16x8 qf[2][4];
#pragma unroll
  for (int qi = 0; qi < 2; ++qi)
#pragma unroll
    for (int ks = 0; ks < 4; ++ks)
      qf[qi][ks] = *(const s16x8*)(qh + (size_t)(qw0 + qi * 16 + lr) * 128 + ks * 32 + lg * 8);

  f32x4 oacc[2][8];
#pragma unroll
  for (int i = 0; i < 2; i++)
#pragma unroll
    for (int j = 0; j < 8; j++) oacc[i][j] = f32x4{0.f, 0.f, 0.f, 0.f};
  float M[2][4], L[2][4];
#pragma unroll
  for (int i = 0; i < 2; i++)
#pragma unroll
    for (int r = 0; r < 4; r++) { M[i][r] = -__builtin_inff(); L[i][r] = 0.f; }

  const float scale_bf = bf16_to_f32(bf16_rne(0.08838834764831845f));

  for (int kt = 0; kt < 64; ++kt) {
#pragma unroll
    for (int i = 0; i < 4; ++i) {
      int c = t + i * 256;
      int row = c >> 4;
      int cc = (c & 15) ^ (row & 7);
      gload_lds16(kh + (size_t)(kt * 64 + row) * 128 + cc * 8, &Ks[c * 8]);
    }
#pragma unroll
    for (int i = 0; i < 4; ++i) {
      int c = t + i * 256;
      int d = c >> 3;
      int cc = (c & 7) ^ (d & 7);
      gload_lds16(vh + (size_t)d * 4096 + kt * 64 + cc * 8, &Vs[c * 8]);
    }
    __syncthreads();

    f32x4 sfr[2][4];
    __builtin_amdgcn_s_setprio(1);
#pragma unroll
    for (int qi = 0; qi < 2; ++qi)
#pragma unroll
      for (int kbl = 0; kbl < 4; ++kbl) {
        f32x4 a = f32x4{0.f, 0.f, 0.f, 0.f};
#pragma unroll
        for (int ks = 0; ks < 4; ++ks) {
          int key = kbl * 16 + lr;
          int byteoff = (key * 256 + (ks * 32 + lg * 8) * 2) ^ ((key & 7) << 4);
          s16x8 bfr = *(const s16x8*)((const char*)Ks + byteoff);
          a = __builtin_amdgcn_mfma_f32_16x16x32_bf16(qf[qi][ks], bfr, a, 0, 0, 0);
        }
        sfr[qi][kbl] = a;
      }
    __builtin_amdgcn_s_setprio(0);

#pragma unroll
    for (int qi = 0; qi < 2; ++qi) {
      float mx[4];
#pragma unroll
      for (int r = 0; r < 4; ++r) {
#pragma unroll
        for (int kbl = 0; kbl < 4; ++kbl) {
          float sv = bf16_to_f32(bf16_rne(sfr[qi][kbl][r])) * scale_bf;
          sfr[qi][kbl][r] = bf16_to_f32(bf16_rne(sv));
        }
        float m0 = fmaxf(fmaxf(sfr[qi][0][r], sfr[qi][1][r]), fmaxf(sfr[qi][2][r], sfr[qi][3][r]));
#pragma unroll
        for (int m = 1; m < 16; m <<= 1) m0 = fmaxf(m0, __shfl_xor(m0, m, 64));
        mx[r] = m0;
      }
      bool ok = (mx[0] - M[qi][0] <= 8.f) && (mx[1] - M[qi][1] <= 8.f) &&
                (mx[2] - M[qi][2] <= 8.f) && (mx[3] - M[qi][3] <= 8.f);
      if (!__all(ok)) {
#pragma unroll
        for (int r = 0; r < 4; ++r) {
          float nm = fmaxf(M[qi][r], mx[r]);
          float fac = __expf(M[qi][r] - nm);
          M[qi][r] = nm;
          L[qi][r] *= fac;
#pragma unroll
          for (int db = 0; db < 8; ++db) oacc[qi][db][r] *= fac;
        }
      }
      float sum[4] = {0.f, 0.f, 0.f, 0.f};
#pragma unroll
      for (int kbl = 0; kbl < 4; ++kbl)
#pragma unroll
        for (int r = 0; r < 4; ++r) {
          float p = __expf(sfr[qi][kbl][r] - M[qi][r]);
          sum[r] += p;
          Ps[w][(qi * 16 + lg * 4 + r) * 72 + kbl * 16 + lr] = bf16_rne(p);
        }
#pragma unroll
      for (int r = 0; r < 4; ++r) {
        float s4 = sum[r];
#pragma unroll
        for (int m = 1; m < 16; m <<= 1) s4 += __shfl_xor(s4, m, 64);
        L[qi][r] += s4;
      }
    }

    asm volatile("s_waitcnt lgkmcnt(0)" ::: "memory");

    s16x8 pa[2][2];
#pragma unroll
    for (int qi = 0; qi < 2; ++qi)
#pragma unroll
      for (int ks = 0; ks < 2; ++ks)
        pa[qi][ks] = *(const s16x8*)&Ps[w][(qi * 16 + lr) * 72 + ks * 32 + lg * 8];
    __builtin_amdgcn_s_setprio(1);
#pragma unroll
    for (int db = 0; db < 8; ++db)
#pragma unroll
      for (int ks = 0; ks < 2; ++ks) {
        int d = db * 16 + lr;
        int byteoff = (d * 128 + (ks * 32 + lg * 8) * 2) ^ ((d & 7) << 4);
        s16x8 vb8 = *(const s16x8*)((const char*)Vs + byteoff);
        oacc[0][db] = __builtin_amdgcn_mfma_f32_16x16x32_bf16(pa[0][ks], vb8, oacc[0][db], 0, 0, 0);
        oacc[1][db] = __builtin_amdgcn_mfma_f32_16x16x32_bf16(pa[1][ks], vb8, oacc[1][db], 0, 0, 0);
      }
    __builtin_amdgcn_s_setprio(0);
    __syncthreads();
  }

#pragma unroll
  for (int qi = 0; qi < 2; ++qi) {
    float rl[4];
#pragma unroll
    for (int r = 0; r < 4; ++r) rl[r] = 1.0f / L[qi][r];
#pragma unroll
    for (int db = 0; db < 8; ++db) {
      int d = db * 16 + lr;
#pragma unroll
      for (int r = 0; r < 4; ++r) {
        int q = qw0 + qi * 16 + lg * 4 + r;
        obf[(size_t)q * 2048 + h * 128 + d] = bf16_rne(oacc[qi][db][r] * rl[r]);
      }
    }
  }
}

// ---------- launch ----------
extern "C" void kernel_launch(void* const* d_in, const int* in_sizes, int n_in,
                              void* d_out, int out_size, void* d_ws, size_t ws_size,
                              hipStream_t stream) {
  const float* x      = (const float*)d_in[0];
  const float* qkv_w  = (const float*)d_in[1];
  const float* qkv_b  = (const float*)d_in[2];
  const float* qnw    = (const float*)d_in[3];
  const float* knw    = (const float*)d_in[4];
  const float* proj_w = (const float*)d_in[5];
  const float* proj_b = (const float*)d_in[6];
  float* out = (float*)d_out;
  char* ws = (char*)d_ws;

  u16* xs    = (u16*)(ws + OFF_XSPLIT);
  u16* wsp   = (u16*)(ws + OFF_WSPLIT);
  u16* pws   = (u16*)(ws + OFF_WSPLIT);
  float* qkf = (float*)(ws + OFF_QKF);
  u16* vb16  = (u16*)(ws + OFF_VB);
  u16* qb16  = (u16*)(ws + OFF_QB);
  u16* kb16  = (u16*)(ws + OFF_KB);
  u16* vt16  = (u16*)(ws + OFF_VT);
  u16* obf   = (u16*)(ws + OFF_XSPLIT);
  float* cosT = (float*)(ws + OFF_COS);
  float* sinT = (float*)(ws + OFF_SIN);

  u16* xsl = xs + (size_t)4096 * 2048;
  u16* wl  = wsp + (size_t)6144 * 2048;
  u16* pl  = pws + (size_t)2048 * 2048;

  k_split<<<2048, 256, 0, stream>>>(x, xs, xsl, 4096 * 2048);
  k_split<<<2048, 256, 0, stream>>>(qkv_w, wsp, wl, 6144 * 2048);
  k_rope_table<<<1024, 256, 0, stream>>>(cosT, sinT);

  // QKV: Xh.Wh + Xh.Wl + Xl.Wh   (48 col-tiles x 32 row-tiles = 1536 blocks)
  k_gemm<0, 48><<<1536, 256, 0, stream>>>(xs, xs, xsl, wsp, wl, wsp,
                                          3, 2048, qkv_b, qkf, vb16);

  k_split<<<2048, 256, 0, stream>>>(proj_w, pws, pl, 2048 * 2048);
  k_norm_rope<<<16384, 256, 0, stream>>>(qkf, qnw, knw, cosT, sinT, qb16, kb16);
  k_transpose_v<<<dim3(64, 16), 256, 0, stream>>>(vb16, vt16);
  k_attn<<<dim3(32, 16), 256, 0, stream>>>(qb16, kb16, vt16, obf);

  // proj: O.Ph + O.Pl   (16 col-tiles x 32 row-tiles = 512 blocks)
  k_gemm<1, 16><<<512, 256, 0, stream>>>(obf, obf, obf, pws, pl, pws,
                                         2, 2048, proj_b, out, nullptr);
}

// Round 6
// 802.688 us; speedup vs baseline: 1.4863x; 1.0455x over previous
//
#include <hip/hip_runtime.h>
#include <hip/hip_bf16.h>

typedef unsigned short u16;
typedef unsigned int u32;
typedef __attribute__((ext_vector_type(8))) short s16x8;
typedef __attribute__((ext_vector_type(4))) float f32x4;
typedef __attribute__((ext_vector_type(2))) float f32x2;
typedef __attribute__((ext_vector_type(4))) unsigned short u16x4;

#define DEV static __device__ __forceinline__

// ---------- helpers ----------
DEV u16 bf16_rne(float f) {
  u32 u = __float_as_uint(f);
  u32 r = 0x7FFFu + ((u >> 16) & 1u);
  return (u16)((u + r) >> 16);
}
DEV float bf16_to_f32(u16 h) { return __uint_as_float(((u32)h) << 16); }

typedef const __attribute__((address_space(1))) u32* gptr_t;
typedef __attribute__((address_space(3))) u32* lptr_t;
DEV void gload_lds16(const void* g, void* l) {
  __builtin_amdgcn_global_load_lds((gptr_t)g, (lptr_t)l, 16, 0, 0);
}

// ---------- workspace layout (bytes) ----------
#define OFF_XSPLIT  0ull
#define OFF_WSPLIT  33554432ull
#define OFF_QKF     83886080ull
#define OFF_VB      150994944ull
#define OFF_QB      167772160ull
#define OFF_KB      184549376ull
#define OFF_VT      201326592ull
#define OFF_COS     218103808ull
#define OFF_SIN     219152384ull

// ---------- split fp32 -> bf16 hi + bf16 lo ----------
__global__ __launch_bounds__(256) void k_split(const float* __restrict__ in,
                                               u16* __restrict__ hi, u16* __restrict__ lo, int n) {
  int i = blockIdx.x * 256 + threadIdx.x;
  int stride = gridDim.x * 256;
  for (; i < n; i += stride) {
    float x = in[i];
    u16 h = bf16_rne(x);
    float xh = bf16_to_f32(h);
    hi[i] = h;
    lo[i] = bf16_rne(x - xh);
  }
}

// ---------- RoPE cos/sin table: (n, 64) ----------
__global__ __launch_bounds__(256) void k_rope_table(float* __restrict__ cosT, float* __restrict__ sinT) {
  int tid = blockIdx.x * 256 + threadIdx.x;
  if (tid >= 4096 * 64) return;
  int n = tid >> 6, j = tid & 63;
  int t = n >> 9, hh = (n >> 5) & 15, ww = n & 31;
  float pos, e;
  if (j < 32)      { pos = (float)t;  e = (float)j * (1.0f / 32.0f); }
  else if (j < 48) { pos = (float)hh; e = (float)(j - 32) * (1.0f / 16.0f); }
  else             { pos = (float)ww; e = (float)(j - 48) * (1.0f / 16.0f); }
  float inv = (float)pow(10000.0, -(double)e);
  float f = pos * inv;
  cosT[tid] = cosf(f);
  sinT[tid] = sinf(f);
}

// ---------- bf16 GEMM, m97 structure: 128x128 tile, BK=32, 4 waves ----------
// 2-D grid: blockIdx.x = col tile (bx%8 -> fixed B-panels per XCD), blockIdx.y = row tile.
// LDS slot-XOR: physical k-slot s holds logical slot s ^ ((row>>1)&3)  (both sides).
template<int MODE>
__global__ __launch_bounds__(256, 2) void k_gemm(
    const u16* __restrict__ A0, const u16* __restrict__ A1, const u16* __restrict__ A2,
    const u16* __restrict__ B0, const u16* __restrict__ B1, const u16* __restrict__ B2,
    int nseg, int K,
    const float* __restrict__ bias,
    float* __restrict__ outF, u16* __restrict__ outV)
{
  __shared__ u16 As[128 * 32];
  __shared__ u16 Bs[128 * 32];
  const int t = threadIdx.x;
  const int lane = t & 63;
  const int lr = lane & 15, lg = lane >> 4;
  const int w = t >> 6;
  const int wr = w >> 1, wc = w & 1;
  const int row0 = blockIdx.y * 128;
  const int col0 = blockIdx.x * 128;

  f32x4 acc[4][4];
#pragma unroll
  for (int m = 0; m < 4; m++)
#pragma unroll
    for (int n = 0; n < 4; n++) acc[m][n] = f32x4{0.f, 0.f, 0.f, 0.f};

  const int c0 = t, c1 = t + 256;
  // pre-permuted source k-part for chunk c: (c&3) ^ ((c>>3)&3)  [row = c>>2]
  const int kp0 = ((c0 & 3) ^ ((c0 >> 3) & 3)) * 8;
  const int kp1 = ((c1 & 3) ^ ((c1 >> 3) & 3)) * 8;
  // fragment read slot: lg ^ ((lr>>1)&3)
  const int slot8 = (lg ^ ((lr >> 1) & 3)) * 8;

  for (int s = 0; s < nseg; ++s) {
    const u16* Ab = (s == 0) ? A0 : (s == 1) ? A1 : A2;
    const u16* Bb = (s == 0) ? B0 : (s == 1) ? B1 : B2;
    const int nkb = K / 32;
    for (int kb = 0; kb < nkb; ++kb) {
      const int k0 = kb * 32;
      gload_lds16(Ab + (size_t)(row0 + (c0 >> 2)) * K + k0 + kp0, &As[c0 * 8]);
      gload_lds16(Ab + (size_t)(row0 + (c1 >> 2)) * K + k0 + kp1, &As[c1 * 8]);
      gload_lds16(Bb + (size_t)(col0 + (c0 >> 2)) * K + k0 + kp0, &Bs[c0 * 8]);
      gload_lds16(Bb + (size_t)(col0 + (c1 >> 2)) * K + k0 + kp1, &Bs[c1 * 8]);
      __syncthreads();
      s16x8 af[4], bf[4];
#pragma unroll
      for (int m = 0; m < 4; m++)
        af[m] = *(const s16x8*)&As[(wr * 64 + m * 16 + lr) * 32 + slot8];
#pragma unroll
      for (int n = 0; n < 4; n++)
        bf[n] = *(const s16x8*)&Bs[(wc * 64 + n * 16 + lr) * 32 + slot8];
      __builtin_amdgcn_s_setprio(1);
#pragma unroll
      for (int m = 0; m < 4; m++)
#pragma unroll
        for (int n = 0; n < 4; n++)
          acc[m][n] = __builtin_amdgcn_mfma_f32_16x16x32_bf16(af[m], bf[n], acc[m][n], 0, 0, 0);
      __builtin_amdgcn_s_setprio(0);
      __syncthreads();
    }
  }

#pragma unroll
  for (int m = 0; m < 4; m++) {
#pragma unroll
    for (int n = 0; n < 4; n++) {
      int col = col0 + wc * 64 + n * 16 + lr;
      float b = bias[col];
#pragma unroll
      for (int r = 0; r < 4; r++) {
        int row = row0 + wr * 64 + m * 16 + lg * 4 + r;
        float v = acc[m][n][r] + b;
        if constexpr (MODE == 0) {
          if (col < 4096) outF[(size_t)row * 4096 + col] = v;
          else            outV[(size_t)row * 2048 + (col - 4096)] = bf16_rne(v);
        } else {
          outF[(size_t)row * 2048 + col] = v;
        }
      }
    }
  }
}

// ---------- RMSNorm (fp32) + RoPE + bf16 cast for q,k. One wave per (n,h). ----------
__global__ __launch_bounds__(256) void k_norm_rope(
    const float* __restrict__ qkf, const float* __restrict__ qw, const float* __restrict__ kw,
    const float* __restrict__ cosT, const float* __restrict__ sinT,
    u16* __restrict__ qb, u16* __restrict__ kb)
{
  int gw = (blockIdx.x * 256 + threadIdx.x) >> 6;
  int lane = threadIdx.x & 63;
  int n = gw >> 4;
  int h = gw & 15;
  float c = cosT[n * 64 + lane];
  float s = sinT[n * 64 + lane];
#pragma unroll
  for (int p = 0; p < 2; ++p) {
    const float* src = qkf + (size_t)n * 4096 + p * 2048 + h * 128;
    f32x2 xv = *(const f32x2*)(src + lane * 2);
    float xr = xv[0], xi = xv[1];
    float ss = xr * xr + xi * xi;
#pragma unroll
    for (int m = 1; m < 64; m <<= 1) ss += __shfl_xor(ss, m, 64);
    float r = 1.0f / sqrtf(ss * (1.0f / 128.0f) + 1e-6f);
    const float* wgt = p ? kw : qw;
    float yr = xr * r * wgt[lane * 2];
    float yi = xi * r * wgt[lane * 2 + 1];
    float o0 = yr * c - yi * s;
    float o1 = yr * s + yi * c;
    u16* dst = (p ? kb : qb) + (size_t)h * 4096 * 128 + (size_t)n * 128 + lane * 2;
    *(u32*)dst = ((u32)bf16_rne(o1) << 16) | bf16_rne(o0);
  }
}

// ---------- V transpose: (n, h*128+d) -> (h, d, n) ----------
__global__ __launch_bounds__(256) void k_transpose_v(const u16* __restrict__ vb, u16* __restrict__ vt) {
  __shared__ u16 Vs[64][136];
  int h = blockIdx.y;
  int n0 = blockIdx.x * 64;
  int t = threadIdx.x;
  int nl = t >> 2, d0 = (t & 3) * 32;
  const u16* src = vb + (size_t)(n0 + nl) * 2048 + h * 128 + d0;
#pragma unroll
  for (int i = 0; i < 8; ++i)
    *(u16x4*)&Vs[nl][d0 + i * 4] = *(const u16x4*)(src + i * 4);
  __syncthreads();
  int d = t >> 1, nc = (t & 1) * 32;
  u16* dst = vt + (size_t)h * 128 * 4096 + (size_t)d * 4096 + n0 + nc;
#pragma unroll
  for (int j4 = 0; j4 < 8; ++j4) {
    u16x4 o;
    o.x = Vs[nc + j4 * 4 + 0][d];
    o.y = Vs[nc + j4 * 4 + 1][d];
    o.z = Vs[nc + j4 * 4 + 2][d];
    o.w = Vs[nc + j4 * 4 + 3][d];
    *(u16x4*)(dst + j4 * 4) = o;
  }
}

// ---------- flash attention: double-buffered K/V staging, head-local XCD mapping ----------
__global__ __launch_bounds__(256, 2) void k_attn(
    const u16* __restrict__ qb, const u16* __restrict__ kb, const u16* __restrict__ vt,
    u16* __restrict__ obf)
{
  __shared__ u16 Ks[2][64 * 128];   // 32 KB, XOR-swizzled rows
  __shared__ u16 Vs[2][128 * 64];   // 32 KB, XOR-swizzled rows
  __shared__ u16 Ps[4][32 * 64];    // 16 KB, per-wave P, XOR-swizzled rows
  const int t = threadIdx.x;
  const int lane = t & 63;
  const int lr = lane & 15, lg = lane >> 4;
  const int w = t >> 6;

  // head-local XCD mapping: all 32 q-tiles of a head land on one XCD
  const int bid = blockIdx.y * 32 + blockIdx.x;     // 0..511
  const int h = (bid & 7) + 8 * ((bid >> 3) >> 5);  // 0..15
  const int qt = (bid >> 3) & 31;                   // 0..31
  const int qw0 = qt * 128 + w * 32;

  const u16* qh = qb + (size_t)h * 4096 * 128;
  const u16* kh = kb + (size_t)h * 4096 * 128;
  const u16* vh = vt + (size_t)h * 128 * 4096;

  s16x8 qf[2][4];
#pragma unroll
  for (int qi = 0; qi < 2; ++qi)
#pragma unroll
    for (int ks = 0; ks < 4; ++ks)
      qf[qi][ks] = *(const s16x8*)(qh + (size_t)(qw0 + qi * 16 + lr) * 128 + ks * 32 + lg * 8);

  f32x4 oacc[2][8];
#pragma unroll
  for (int i = 0; i < 2; i++)
#pragma unroll
    for (int j = 0; j < 8; j++) oacc[i][j] = f32x4{0.f, 0.f, 0.f, 0.f};
  float M[2][4], L[2][4];
#pragma unroll
  for (int i = 0; i < 2; i++)
#pragma unroll
    for (int r = 0; r < 4; r++) { M[i][r] = -__builtin_inff(); L[i][r] = 0.f; }

  const float scale_bf = bf16_to_f32(bf16_rne(0.08838834764831845f));

  auto stageKV = [&](int kt, int b) __attribute__((always_inline)) {
#pragma unroll
    for (int i = 0; i < 4; ++i) {
      int c = t + i * 256;
      int row = c >> 4;
      int cc = (c & 15) ^ (row & 7);
      gload_lds16(kh + (size_t)(kt * 64 + row) * 128 + cc * 8, &Ks[b][c * 8]);
    }
#pragma unroll
    for (int i = 0; i < 4; ++i) {
      int c = t + i * 256;
      int d = c >> 3;
      int cc = (c & 7) ^ (d & 7);
      gload_lds16(vh + (size_t)d * 4096 + kt * 64 + cc * 8, &Vs[b][c * 8]);
    }
  };

  stageKV(0, 0);
  __syncthreads();   // vmcnt(0) drain + barrier

  for (int kt = 0; kt < 64; ++kt) {
    const int b = kt & 1;
    if (kt + 1 < 64) stageKV(kt + 1, b ^ 1);   // latency hides under compute below

    // S = Q . K^T  (2 q-blocks x 4 key-blocks of 16x16)
    f32x4 sfr[2][4];
    __builtin_amdgcn_s_setprio(1);
#pragma unroll
    for (int qi = 0; qi < 2; ++qi)
#pragma unroll
      for (int kbl = 0; kbl < 4; ++kbl) {
        f32x4 a = f32x4{0.f, 0.f, 0.f, 0.f};
#pragma unroll
        for (int ks = 0; ks < 4; ++ks) {
          int key = kbl * 16 + lr;
          int byteoff = (key * 256 + (ks * 32 + lg * 8) * 2) ^ ((key & 7) << 4);
          s16x8 bfr = *(const s16x8*)((const char*)&Ks[b][0] + byteoff);
          a = __builtin_amdgcn_mfma_f32_16x16x32_bf16(qf[qi][ks], bfr, a, 0, 0, 0);
        }
        sfr[qi][kbl] = a;
      }
    __builtin_amdgcn_s_setprio(0);

    // online softmax; scores double-rounded to bf16, native exp, defer-max (THR=8)
#pragma unroll
    for (int qi = 0; qi < 2; ++qi) {
      float mx[4];
#pragma unroll
      for (int r = 0; r < 4; ++r) {
#pragma unroll
        for (int kbl = 0; kbl < 4; ++kbl) {
          float sv = bf16_to_f32(bf16_rne(sfr[qi][kbl][r])) * scale_bf;
          sfr[qi][kbl][r] = bf16_to_f32(bf16_rne(sv));
        }
        float m0 = fmaxf(fmaxf(sfr[qi][0][r], sfr[qi][1][r]), fmaxf(sfr[qi][2][r], sfr[qi][3][r]));
#pragma unroll
        for (int m = 1; m < 16; m <<= 1) m0 = fmaxf(m0, __shfl_xor(m0, m, 64));
        mx[r] = m0;
      }
      bool ok = (mx[0] - M[qi][0] <= 8.f) && (mx[1] - M[qi][1] <= 8.f) &&
                (mx[2] - M[qi][2] <= 8.f) && (mx[3] - M[qi][3] <= 8.f);
      if (!__all(ok)) {
#pragma unroll
        for (int r = 0; r < 4; ++r) {
          float nm = fmaxf(M[qi][r], mx[r]);
          float fac = __expf(M[qi][r] - nm);
          M[qi][r] = nm;
          L[qi][r] *= fac;
#pragma unroll
          for (int db = 0; db < 8; ++db) oacc[qi][db][r] *= fac;
        }
      }
      float sum[4] = {0.f, 0.f, 0.f, 0.f};
#pragma unroll
      for (int kbl = 0; kbl < 4; ++kbl)
#pragma unroll
        for (int r = 0; r < 4; ++r) {
          float p = __expf(sfr[qi][kbl][r] - M[qi][r]);
          sum[r] += p;
          int prow = qi * 16 + lg * 4 + r;
          Ps[w][prow * 64 + ((kbl * 16 + lr) ^ (((lg * 4 + r) & 7) << 3))] = bf16_rne(p);
        }
#pragma unroll
      for (int r = 0; r < 4; ++r) {
        float s4 = sum[r];
#pragma unroll
        for (int m = 1; m < 16; m <<= 1) s4 += __shfl_xor(s4, m, 64);
        L[qi][r] += s4;
      }
    }

    asm volatile("s_waitcnt lgkmcnt(0)" ::: "memory");   // P writes visible to own-wave reads

    // PV: O += P (32x64) . V (64x128)
    s16x8 pa[2][2];
#pragma unroll
    for (int qi = 0; qi < 2; ++qi)
#pragma unroll
      for (int ks = 0; ks < 2; ++ks) {
        int prow = qi * 16 + lr;
        pa[qi][ks] = *(const s16x8*)&Ps[w][prow * 64 + ((ks * 32 + lg * 8) ^ ((lr & 7) << 3))];
      }
    __builtin_amdgcn_s_setprio(1);
#pragma unroll
    for (int db = 0; db < 8; ++db)
#pragma unroll
      for (int ks = 0; ks < 2; ++ks) {
        int d = db * 16 + lr;
        int byteoff = (d * 128 + (ks * 32 + lg * 8) * 2) ^ ((d & 7) << 4);
        s16x8 vb8 = *(const s16x8*)((const char*)&Vs[b][0] + byteoff);
        oacc[0][db] = __builtin_amdgcn_mfma_f32_16x16x32_bf16(pa[0][ks], vb8, oacc[0][db], 0, 0, 0);
        oacc[1][db] = __builtin_amdgcn_mfma_f32_16x16x32_bf16(pa[1][ks], vb8, oacc[1][db], 0, 0, 0);
      }
    __builtin_amdgcn_s_setprio(0);
    __syncthreads();   // drains this iter's stage (vmcnt 0) -> next buffer ready
  }

  // normalize + store bf16 (n, h*128+d)
#pragma unroll
  for (int qi = 0; qi < 2; ++qi) {
    float rl[4];
#pragma unroll
    for (int r = 0; r < 4; ++r) rl[r] = 1.0f / L[qi][r];
#pragma unroll
    for (int db = 0; db < 8; ++db) {
      int d = db * 16 + lr;
#pragma unroll
      for (int r = 0; r < 4; ++r) {
        int q = qw0 + qi * 16 + lg * 4 + r;
        obf[(size_t)q * 2048 + h * 128 + d] = bf16_rne(oacc[qi][db][r] * rl[r]);
      }
    }
  }
}

// ---------- launch ----------
extern "C" void kernel_launch(void* const* d_in, const int* in_sizes, int n_in,
                              void* d_out, int out_size, void* d_ws, size_t ws_size,
                              hipStream_t stream) {
  const float* x      = (const float*)d_in[0];
  const float* qkv_w  = (const float*)d_in[1];
  const float* qkv_b  = (const float*)d_in[2];
  const float* qnw    = (const float*)d_in[3];
  const float* knw    = (const float*)d_in[4];
  const float* proj_w = (const float*)d_in[5];
  const float* proj_b = (const float*)d_in[6];
  float* out = (float*)d_out;
  char* ws = (char*)d_ws;

  u16* xs    = (u16*)(ws + OFF_XSPLIT);
  u16* wsp   = (u16*)(ws + OFF_WSPLIT);
  u16* pws   = (u16*)(ws + OFF_WSPLIT);
  float* qkf = (float*)(ws + OFF_QKF);
  u16* vb16  = (u16*)(ws + OFF_VB);
  u16* qb16  = (u16*)(ws + OFF_QB);
  u16* kb16  = (u16*)(ws + OFF_KB);
  u16* vt16  = (u16*)(ws + OFF_VT);
  u16* obf   = (u16*)(ws + OFF_XSPLIT);
  float* cosT = (float*)(ws + OFF_COS);
  float* sinT = (float*)(ws + OFF_SIN);

  u16* xsl = xs + (size_t)4096 * 2048;
  u16* wl  = wsp + (size_t)6144 * 2048;
  u16* pl  = pws + (size_t)2048 * 2048;

  k_split<<<2048, 256, 0, stream>>>(x, xs, xsl, 4096 * 2048);
  k_split<<<2048, 256, 0, stream>>>(qkv_w, wsp, wl, 6144 * 2048);
  k_rope_table<<<1024, 256, 0, stream>>>(cosT, sinT);

  // QKV: Xh.Wh + Xh.Wl + Xl.Wh
  k_gemm<0><<<dim3(48, 32), 256, 0, stream>>>(xs, xs, xsl, wsp, wl, wsp,
                                              3, 2048, qkv_b, qkf, vb16);

  k_split<<<2048, 256, 0, stream>>>(proj_w, pws, pl, 2048 * 2048);
  k_norm_rope<<<16384, 256, 0, stream>>>(qkf, qnw, knw, cosT, sinT, qb16, kb16);
  k_transpose_v<<<dim3(64, 16), 256, 0, stream>>>(vb16, vt16);
  k_attn<<<dim3(32, 16), 256, 0, stream>>>(qb16, kb16, vt16, obf);

  // proj: O.Ph + O.Pl
  k_gemm<1><<<dim3(16, 32), 256, 0, stream>>>(obf, obf, obf, pws, pl, pws,
                                              2, 2048, proj_b, out, nullptr);
}

// Round 8
// 714.129 us; speedup vs baseline: 1.6706x; 1.1240x over previous
//
#include <hip/hip_runtime.h>
#include <hip/hip_bf16.h>
#include <hip/hip_fp16.h>

typedef unsigned short u16;
typedef unsigned int u32;
typedef __attribute__((ext_vector_type(8))) short s16x8;
typedef __attribute__((ext_vector_type(8))) _Float16 f16x8;
typedef __attribute__((ext_vector_type(4))) float f32x4;
typedef __attribute__((ext_vector_type(2))) float f32x2;
typedef __attribute__((ext_vector_type(4))) unsigned short u16x4;

#define DEV static __device__ __forceinline__

// ---------- helpers ----------
DEV u16 bf16_rne(float f) {
  u32 u = __float_as_uint(f);
  u32 r = 0x7FFFu + ((u >> 16) & 1u);
  return (u16)((u + r) >> 16);
}
DEV float bf16_to_f32(u16 h) { return __uint_as_float(((u32)h) << 16); }

typedef const __attribute__((address_space(1))) u32* gptr_t;
typedef __attribute__((address_space(3))) u32* lptr_t;
DEV void gload_lds16(const void* g, void* l) {
  __builtin_amdgcn_global_load_lds((gptr_t)g, (lptr_t)l, 16, 0, 0);
}

// ---------- workspace layout (bytes) ----------
#define OFF_XSPLIT  0ull                 // 2 * 4096*2048 u16 = 33.5 MB (Xh|Xl) ; reused as obf (fp16)
#define OFF_WSPLIT  33554432ull          // 2 * 6144*2048 u16 = 50.3 MB (Wh|Wl) ; reused as pwh (fp16)
#define OFF_QKF     83886080ull          // 4096*4096 f32 ([q|k] fp32)
#define OFF_VB      150994944ull         // v bf16 (n,h,d)
#define OFF_QB      167772160ull         // q bf16 (h,n,d)
#define OFF_KB      184549376ull         // k bf16 (h,n,d)
#define OFF_VT      201326592ull         // v bf16 (h,d,n)
#define OFF_COS     218103808ull
#define OFF_SIN     219152384ull

// ---------- split fp32 -> bf16 hi + bf16 lo ----------
__global__ __launch_bounds__(256) void k_split(const float* __restrict__ in,
                                               u16* __restrict__ hi, u16* __restrict__ lo, int n) {
  int i = blockIdx.x * 256 + threadIdx.x;
  int stride = gridDim.x * 256;
  for (; i < n; i += stride) {
    float x = in[i];
    u16 h = bf16_rne(x);
    float xh = bf16_to_f32(h);
    hi[i] = h;
    lo[i] = bf16_rne(x - xh);
  }
}

// ---------- fp32 -> fp16 convert (RNE) ----------
__global__ __launch_bounds__(256) void k_cvt16(const float* __restrict__ in,
                                               u16* __restrict__ out, int n4) {
  int i = blockIdx.x * 256 + threadIdx.x;
  int stride = gridDim.x * 256;
  for (; i < n4; i += stride) {
    f32x4 v = *(const f32x4*)(in + (size_t)i * 4);
    u16x4 o;
#pragma unroll
    for (int j = 0; j < 4; ++j) {
      __half h = __float2half(v[j]);
      o[j] = *(u16*)&h;
    }
    *(u16x4*)(out + (size_t)i * 4) = o;
  }
}

// ---------- RoPE cos/sin table: (n, 64) ----------
__global__ __launch_bounds__(256) void k_rope_table(float* __restrict__ cosT, float* __restrict__ sinT) {
  int tid = blockIdx.x * 256 + threadIdx.x;
  if (tid >= 4096 * 64) return;
  int n = tid >> 6, j = tid & 63;
  int t = n >> 9, hh = (n >> 5) & 15, ww = n & 31;
  float pos, e;
  if (j < 32)      { pos = (float)t;  e = (float)j * (1.0f / 32.0f); }
  else if (j < 48) { pos = (float)hh; e = (float)(j - 32) * (1.0f / 16.0f); }
  else             { pos = (float)ww; e = (float)(j - 48) * (1.0f / 16.0f); }
  float inv = (float)pow(10000.0, -(double)e);
  float f = pos * inv;
  cosT[tid] = cosf(f);
  sinT[tid] = sinf(f);
}

// ---------- QKV GEMM: fused 3-segment bf16 hi/lo (Xh.Wh + Xh.Wl + Xl.Wh) ----------
// m97 128x128 tile, BK=32, 4 waves; all 4 operand tiles staged once per k-block.
// 2-D grid (48,32): bx%8 -> fixed B-panels per XCD. Slot-XOR conflict-free LDS (r6).
__global__ __launch_bounds__(256, 2) void k_gemm_qkv(
    const u16* __restrict__ Ah_, const u16* __restrict__ Al_,
    const u16* __restrict__ Bh_, const u16* __restrict__ Bl_,
    const float* __restrict__ bias,
    float* __restrict__ outF, u16* __restrict__ outV)
{
  __shared__ u16 AsH[128 * 32];
  __shared__ u16 AsL[128 * 32];
  __shared__ u16 BsH[128 * 32];
  __shared__ u16 BsL[128 * 32];
  const int t = threadIdx.x;
  const int lane = t & 63;
  const int lr = lane & 15, lg = lane >> 4;
  const int w = t >> 6;
  const int wr = w >> 1, wc = w & 1;
  const int row0 = blockIdx.y * 128;
  const int col0 = blockIdx.x * 128;
  const int K = 2048;

  f32x4 acc[4][4];
#pragma unroll
  for (int m = 0; m < 4; m++)
#pragma unroll
    for (int n = 0; n < 4; n++) acc[m][n] = f32x4{0.f, 0.f, 0.f, 0.f};

  const int c0 = t, c1 = t + 256;
  const int kp0 = ((c0 & 3) ^ ((c0 >> 3) & 3)) * 8;
  const int kp1 = ((c1 & 3) ^ ((c1 >> 3) & 3)) * 8;
  const int slot8 = (lg ^ ((lr >> 1) & 3)) * 8;
  const size_t ar0 = (size_t)(row0 + (c0 >> 2)) * K;
  const size_t ar1 = (size_t)(row0 + (c1 >> 2)) * K;
  const size_t br0 = (size_t)(col0 + (c0 >> 2)) * K;
  const size_t br1 = (size_t)(col0 + (c1 >> 2)) * K;

  for (int kb = 0; kb < 64; ++kb) {
    const int k0 = kb * 32;
    gload_lds16(Ah_ + ar0 + k0 + kp0, &AsH[c0 * 8]);
    gload_lds16(Ah_ + ar1 + k0 + kp1, &AsH[c1 * 8]);
    gload_lds16(Al_ + ar0 + k0 + kp0, &AsL[c0 * 8]);
    gload_lds16(Al_ + ar1 + k0 + kp1, &AsL[c1 * 8]);
    gload_lds16(Bh_ + br0 + k0 + kp0, &BsH[c0 * 8]);
    gload_lds16(Bh_ + br1 + k0 + kp1, &BsH[c1 * 8]);
    gload_lds16(Bl_ + br0 + k0 + kp0, &BsL[c0 * 8]);
    gload_lds16(Bl_ + br1 + k0 + kp1, &BsL[c1 * 8]);
    __syncthreads();
    s16x8 ah[4], al[4], bh[4], bl[4];
#pragma unroll
    for (int m = 0; m < 4; m++) {
      ah[m] = *(const s16x8*)&AsH[(wr * 64 + m * 16 + lr) * 32 + slot8];
      al[m] = *(const s16x8*)&AsL[(wr * 64 + m * 16 + lr) * 32 + slot8];
    }
#pragma unroll
    for (int n = 0; n < 4; n++) {
      bh[n] = *(const s16x8*)&BsH[(wc * 64 + n * 16 + lr) * 32 + slot8];
      bl[n] = *(const s16x8*)&BsL[(wc * 64 + n * 16 + lr) * 32 + slot8];
    }
    __builtin_amdgcn_s_setprio(1);
#pragma unroll
    for (int m = 0; m < 4; m++)
#pragma unroll
      for (int n = 0; n < 4; n++) {
        acc[m][n] = __builtin_amdgcn_mfma_f32_16x16x32_bf16(ah[m], bh[n], acc[m][n], 0, 0, 0);
        acc[m][n] = __builtin_amdgcn_mfma_f32_16x16x32_bf16(ah[m], bl[n], acc[m][n], 0, 0, 0);
        acc[m][n] = __builtin_amdgcn_mfma_f32_16x16x32_bf16(al[m], bh[n], acc[m][n], 0, 0, 0);
      }
    __builtin_amdgcn_s_setprio(0);
    __syncthreads();
  }

#pragma unroll
  for (int m = 0; m < 4; m++) {
#pragma unroll
    for (int n = 0; n < 4; n++) {
      int col = col0 + wc * 64 + n * 16 + lr;
      float b = bias[col];
#pragma unroll
      for (int r = 0; r < 4; r++) {
        int row = row0 + wr * 64 + m * 16 + lg * 4 + r;
        float v = acc[m][n][r] + b;
        if (col < 4096) outF[(size_t)row * 4096 + col] = v;
        else            outV[(size_t)row * 2048 + (col - 4096)] = bf16_rne(v);
      }
    }
  }
}

// ---------- proj GEMM: fp16 single segment (o is bf16-exact in fp16; only w rounded) ----------
__global__ __launch_bounds__(256, 2) void k_gemm_proj(
    const u16* __restrict__ A, const u16* __restrict__ B,
    const float* __restrict__ bias, float* __restrict__ outF)
{
  __shared__ u16 As[128 * 32];
  __shared__ u16 Bs[128 * 32];
  const int t = threadIdx.x;
  const int lane = t & 63;
  const int lr = lane & 15, lg = lane >> 4;
  const int w = t >> 6;
  const int wr = w >> 1, wc = w & 1;
  const int row0 = blockIdx.y * 128;
  const int col0 = blockIdx.x * 128;
  const int K = 2048;

  f32x4 acc[4][4];
#pragma unroll
  for (int m = 0; m < 4; m++)
#pragma unroll
    for (int n = 0; n < 4; n++) acc[m][n] = f32x4{0.f, 0.f, 0.f, 0.f};

  const int c0 = t, c1 = t + 256;
  const int kp0 = ((c0 & 3) ^ ((c0 >> 3) & 3)) * 8;
  const int kp1 = ((c1 & 3) ^ ((c1 >> 3) & 3)) * 8;
  const int slot8 = (lg ^ ((lr >> 1) & 3)) * 8;

  for (int kb = 0; kb < 64; ++kb) {
    const int k0 = kb * 32;
    gload_lds16(A + (size_t)(row0 + (c0 >> 2)) * K + k0 + kp0, &As[c0 * 8]);
    gload_lds16(A + (size_t)(row0 + (c1 >> 2)) * K + k0 + kp1, &As[c1 * 8]);
    gload_lds16(B + (size_t)(col0 + (c0 >> 2)) * K + k0 + kp0, &Bs[c0 * 8]);
    gload_lds16(B + (size_t)(col0 + (c1 >> 2)) * K + k0 + kp1, &Bs[c1 * 8]);
    __syncthreads();
    f16x8 af[4], bf[4];
#pragma unroll
    for (int m = 0; m < 4; m++)
      af[m] = *(const f16x8*)&As[(wr * 64 + m * 16 + lr) * 32 + slot8];
#pragma unroll
    for (int n = 0; n < 4; n++)
      bf[n] = *(const f16x8*)&Bs[(wc * 64 + n * 16 + lr) * 32 + slot8];
    __builtin_amdgcn_s_setprio(1);
#pragma unroll
    for (int m = 0; m < 4; m++)
#pragma unroll
      for (int n = 0; n < 4; n++)
        acc[m][n] = __builtin_amdgcn_mfma_f32_16x16x32_f16(af[m], bf[n], acc[m][n], 0, 0, 0);
    __builtin_amdgcn_s_setprio(0);
    __syncthreads();
  }

#pragma unroll
  for (int m = 0; m < 4; m++) {
#pragma unroll
    for (int n = 0; n < 4; n++) {
      int col = col0 + wc * 64 + n * 16 + lr;
      float b = bias[col];
#pragma unroll
      for (int r = 0; r < 4; r++) {
        int row = row0 + wr * 64 + m * 16 + lg * 4 + r;
        outF[(size_t)row * 2048 + col] = acc[m][n][r] + b;
      }
    }
  }
}

// ---------- RMSNorm (fp32) + RoPE + bf16 cast for q,k. One wave per (n,h). ----------
__global__ __launch_bounds__(256) void k_norm_rope(
    const float* __restrict__ qkf, const float* __restrict__ qw, const float* __restrict__ kw,
    const float* __restrict__ cosT, const float* __restrict__ sinT,
    u16* __restrict__ qb, u16* __restrict__ kb)
{
  int gw = (blockIdx.x * 256 + threadIdx.x) >> 6;
  int lane = threadIdx.x & 63;
  int n = gw >> 4;
  int h = gw & 15;
  float c = cosT[n * 64 + lane];
  float s = sinT[n * 64 + lane];
#pragma unroll
  for (int p = 0; p < 2; ++p) {
    const float* src = qkf + (size_t)n * 4096 + p * 2048 + h * 128;
    f32x2 xv = *(const f32x2*)(src + lane * 2);
    float xr = xv[0], xi = xv[1];
    float ss = xr * xr + xi * xi;
#pragma unroll
    for (int m = 1; m < 64; m <<= 1) ss += __shfl_xor(ss, m, 64);
    float r = 1.0f / sqrtf(ss * (1.0f / 128.0f) + 1e-6f);
    const float* wgt = p ? kw : qw;
    float yr = xr * r * wgt[lane * 2];
    float yi = xi * r * wgt[lane * 2 + 1];
    float o0 = yr * c - yi * s;
    float o1 = yr * s + yi * c;
    u16* dst = (p ? kb : qb) + (size_t)h * 4096 * 128 + (size_t)n * 128 + lane * 2;
    *(u32*)dst = ((u32)bf16_rne(o1) << 16) | bf16_rne(o0);
  }
}

// ---------- V transpose: (n, h*128+d) -> (h, d, n) ----------
__global__ __launch_bounds__(256) void k_transpose_v(const u16* __restrict__ vb, u16* __restrict__ vt) {
  __shared__ u16 Vs[64][136];
  int h = blockIdx.y;
  int n0 = blockIdx.x * 64;
  int t = threadIdx.x;
  int nl = t >> 2, d0 = (t & 3) * 32;
  const u16* src = vb + (size_t)(n0 + nl) * 2048 + h * 128 + d0;
#pragma unroll
  for (int i = 0; i < 8; ++i)
    *(u16x4*)&Vs[nl][d0 + i * 4] = *(const u16x4*)(src + i * 4);
  __syncthreads();
  int d = t >> 1, nc = (t & 1) * 32;
  u16* dst = vt + (size_t)h * 128 * 4096 + (size_t)d * 4096 + n0 + nc;
#pragma unroll
  for (int j4 = 0; j4 < 8; ++j4) {
    u16x4 o;
    o.x = Vs[nc + j4 * 4 + 0][d];
    o.y = Vs[nc + j4 * 4 + 1][d];
    o.z = Vs[nc + j4 * 4 + 2][d];
    o.w = Vs[nc + j4 * 4 + 3][d];
    *(u16x4*)(dst + j4 * 4) = o;
  }
}

// ---------- flash attention: double-buffered K/V staging, head-local XCD mapping ----------
// epilogue stores o as FP16 bits of the bf16-rounded value (exact conversion) for the fp16 proj GEMM.
__global__ __launch_bounds__(256, 2) void k_attn(
    const u16* __restrict__ qb, const u16* __restrict__ kb, const u16* __restrict__ vt,
    u16* __restrict__ obf)
{
  __shared__ u16 Ks[2][64 * 128];
  __shared__ u16 Vs[2][128 * 64];
  __shared__ u16 Ps[4][32 * 64];
  const int t = threadIdx.x;
  const int lane = t & 63;
  const int lr = lane & 15, lg = lane >> 4;
  const int w = t >> 6;

  const int bid = blockIdx.y * 32 + blockIdx.x;
  const int h = (bid & 7) + 8 * ((bid >> 3) >> 5);
  const int qt = (bid >> 3) & 31;
  const int qw0 = qt * 128 + w * 32;

  const u16* qh = qb + (size_t)h * 4096 * 128;
  const u16* kh = kb + (size_t)h * 4096 * 128;
  const u16* vh = vt + (size_t)h * 128 * 4096;

  s16x8 qf[2][4];
#pragma unroll
  for (int qi = 0; qi < 2; ++qi)
#pragma unroll
    for (int ks = 0; ks < 4; ++ks)
      qf[qi][ks] = *(const s16x8*)(qh + (size_t)(qw0 + qi * 16 + lr) * 128 + ks * 32 + lg * 8);

  f32x4 oacc[2][8];
#pragma unroll
  for (int i = 0; i < 2; i++)
#pragma unroll
    for (int j = 0; j < 8; j++) oacc[i][j] = f32x4{0.f, 0.f, 0.f, 0.f};
  float M[2][4], L[2][4];
#pragma unroll
  for (int i = 0; i < 2; i++)
#pragma unroll
    for (int r = 0; r < 4; r++) { M[i][r] = -__builtin_inff(); L[i][r] = 0.f; }

  const float scale_bf = bf16_to_f32(bf16_rne(0.08838834764831845f));

  auto stageKV = [&](int kt, int b) __attribute__((always_inline)) {
#pragma unroll
    for (int i = 0; i < 4; ++i) {
      int c = t + i * 256;
      int row = c >> 4;
      int cc = (c & 15) ^ (row & 7);
      gload_lds16(kh + (size_t)(kt * 64 + row) * 128 + cc * 8, &Ks[b][c * 8]);
    }
#pragma unroll
    for (int i = 0; i < 4; ++i) {
      int c = t + i * 256;
      int d = c >> 3;
      int cc = (c & 7) ^ (d & 7);
      gload_lds16(vh + (size_t)d * 4096 + kt * 64 + cc * 8, &Vs[b][c * 8]);
    }
  };

  stageKV(0, 0);
  __syncthreads();

  for (int kt = 0; kt < 64; ++kt) {
    const int b = kt & 1;
    if (kt + 1 < 64) stageKV(kt + 1, b ^ 1);

    f32x4 sfr[2][4];
    __builtin_amdgcn_s_setprio(1);
#pragma unroll
    for (int qi = 0; qi < 2; ++qi)
#pragma unroll
      for (int kbl = 0; kbl < 4; ++kbl) {
        f32x4 a = f32x4{0.f, 0.f, 0.f, 0.f};
#pragma unroll
        for (int ks = 0; ks < 4; ++ks) {
          int key = kbl * 16 + lr;
          int byteoff = (key * 256 + (ks * 32 + lg * 8) * 2) ^ ((key & 7) << 4);
          s16x8 bfr = *(const s16x8*)((const char*)&Ks[b][0] + byteoff);
          a = __builtin_amdgcn_mfma_f32_16x16x32_bf16(qf[qi][ks], bfr, a, 0, 0, 0);
        }
        sfr[qi][kbl] = a;
      }
    __builtin_amdgcn_s_setprio(0);

#pragma unroll
    for (int qi = 0; qi < 2; ++qi) {
      float mx[4];
#pragma unroll
      for (int r = 0; r < 4; ++r) {
#pragma unroll
        for (int kbl = 0; kbl < 4; ++kbl) {
          float sv = bf16_to_f32(bf16_rne(sfr[qi][kbl][r])) * scale_bf;
          sfr[qi][kbl][r] = bf16_to_f32(bf16_rne(sv));
        }
        float m0 = fmaxf(fmaxf(sfr[qi][0][r], sfr[qi][1][r]), fmaxf(sfr[qi][2][r], sfr[qi][3][r]));
#pragma unroll
        for (int m = 1; m < 16; m <<= 1) m0 = fmaxf(m0, __shfl_xor(m0, m, 64));
        mx[r] = m0;
      }
      bool ok = (mx[0] - M[qi][0] <= 8.f) && (mx[1] - M[qi][1] <= 8.f) &&
                (mx[2] - M[qi][2] <= 8.f) && (mx[3] - M[qi][3] <= 8.f);
      if (!__all(ok)) {
#pragma unroll
        for (int r = 0; r < 4; ++r) {
          float nm = fmaxf(M[qi][r], mx[r]);
          float fac = __expf(M[qi][r] - nm);
          M[qi][r] = nm;
          L[qi][r] *= fac;
#pragma unroll
          for (int db = 0; db < 8; ++db) oacc[qi][db][r] *= fac;
        }
      }
      float sum[4] = {0.f, 0.f, 0.f, 0.f};
#pragma unroll
      for (int kbl = 0; kbl < 4; ++kbl)
#pragma unroll
        for (int r = 0; r < 4; ++r) {
          float p = __expf(sfr[qi][kbl][r] - M[qi][r]);
          sum[r] += p;
          int prow = qi * 16 + lg * 4 + r;
          Ps[w][prow * 64 + ((kbl * 16 + lr) ^ (((lg * 4 + r) & 7) << 3))] = bf16_rne(p);
        }
#pragma unroll
      for (int r = 0; r < 4; ++r) {
        float s4 = sum[r];
#pragma unroll
        for (int m = 1; m < 16; m <<= 1) s4 += __shfl_xor(s4, m, 64);
        L[qi][r] += s4;
      }
    }

    asm volatile("s_waitcnt lgkmcnt(0)" ::: "memory");

    s16x8 pa[2][2];
#pragma unroll
    for (int qi = 0; qi < 2; ++qi)
#pragma unroll
      for (int ks = 0; ks < 2; ++ks) {
        int prow = qi * 16 + lr;
        pa[qi][ks] = *(const s16x8*)&Ps[w][prow * 64 + ((ks * 32 + lg * 8) ^ ((lr & 7) << 3))];
      }
    __builtin_amdgcn_s_setprio(1);
#pragma unroll
    for (int db = 0; db < 8; ++db)
#pragma unroll
      for (int ks = 0; ks < 2; ++ks) {
        int d = db * 16 + lr;
        int byteoff = (d * 128 + (ks * 32 + lg * 8) * 2) ^ ((d & 7) << 4);
        s16x8 vb8 = *(const s16x8*)((const char*)&Vs[b][0] + byteoff);
        oacc[0][db] = __builtin_amdgcn_mfma_f32_16x16x32_bf16(pa[0][ks], vb8, oacc[0][db], 0, 0, 0);
        oacc[1][db] = __builtin_amdgcn_mfma_f32_16x16x32_bf16(pa[1][ks], vb8, oacc[1][db], 0, 0, 0);
      }
    __builtin_amdgcn_s_setprio(0);
    __syncthreads();
  }

  // normalize + round to bf16 (matches ref) + store as FP16 bits (exact bf16->fp16)
#pragma unroll
  for (int qi = 0; qi < 2; ++qi) {
    float rl[4];
#pragma unroll
    for (int r = 0; r < 4; ++r) rl[r] = 1.0f / L[qi][r];
#pragma unroll
    for (int db = 0; db < 8; ++db) {
      int d = db * 16 + lr;
#pragma unroll
      for (int r = 0; r < 4; ++r) {
        int q = qw0 + qi * 16 + lg * 4 + r;
        float obf16 = bf16_to_f32(bf16_rne(oacc[qi][db][r] * rl[r]));
        __half hh = __float2half(obf16);
        obf[(size_t)q * 2048 + h * 128 + d] = *(u16*)&hh;
      }
    }
  }
}

// ---------- launch ----------
extern "C" void kernel_launch(void* const* d_in, const int* in_sizes, int n_in,
                              void* d_out, int out_size, void* d_ws, size_t ws_size,
                              hipStream_t stream) {
  const float* x      = (const float*)d_in[0];
  const float* qkv_w  = (const float*)d_in[1];
  const float* qkv_b  = (const float*)d_in[2];
  const float* qnw    = (const float*)d_in[3];
  const float* knw    = (const float*)d_in[4];
  const float* proj_w = (const float*)d_in[5];
  const float* proj_b = (const float*)d_in[6];
  float* out = (float*)d_out;
  char* ws = (char*)d_ws;

  u16* xs    = (u16*)(ws + OFF_XSPLIT);
  u16* wsp   = (u16*)(ws + OFF_WSPLIT);
  u16* pwh   = (u16*)(ws + OFF_WSPLIT);   // fp16 proj_w, reuse after QKV GEMM
  float* qkf = (float*)(ws + OFF_QKF);
  u16* vb16  = (u16*)(ws + OFF_VB);
  u16* qb16  = (u16*)(ws + OFF_QB);
  u16* kb16  = (u16*)(ws + OFF_KB);
  u16* vt16  = (u16*)(ws + OFF_VT);
  u16* obf   = (u16*)(ws + OFF_XSPLIT);   // fp16 o, reuse (x splits dead after QKV GEMM)
  float* cosT = (float*)(ws + OFF_COS);
  float* sinT = (float*)(ws + OFF_SIN);

  u16* xsl = xs + (size_t)4096 * 2048;
  u16* wl  = wsp + (size_t)6144 * 2048;

  k_split<<<2048, 256, 0, stream>>>(x, xs, xsl, 4096 * 2048);
  k_split<<<2048, 256, 0, stream>>>(qkv_w, wsp, wl, 6144 * 2048);
  k_rope_table<<<1024, 256, 0, stream>>>(cosT, sinT);

  // QKV: fused 3-segment bf16 hi/lo
  k_gemm_qkv<<<dim3(48, 32), 256, 0, stream>>>(xs, xsl, wsp, wl, qkv_b, qkf, vb16);

  k_cvt16<<<2048, 256, 0, stream>>>(proj_w, pwh, 2048 * 2048 / 4);
  k_norm_rope<<<16384, 256, 0, stream>>>(qkf, qnw, knw, cosT, sinT, qb16, kb16);
  k_transpose_v<<<dim3(64, 16), 256, 0, stream>>>(vb16, vt16);
  k_attn<<<dim3(32, 16), 256, 0, stream>>>(qb16, kb16, vt16, obf);

  // proj: fp16 single segment
  k_gemm_proj<<<dim3(16, 32), 256, 0, stream>>>(obf, pwh, proj_b, out);
}